// Round 1
// baseline (910.998 us; speedup 1.0000x reference)
//
#include <hip/hip_runtime.h>
#include <hip/hip_bf16.h>
#include <cstdint>

#define D     2048
#define NP    64
#define NC    32
#define T     16384

// d_out float offsets (y, props, satisfaction, consistency, loss)
#define Y_OFF   0
#define P_OFF   33554432
#define S_OFF   34603008
#define C_OFF   35127296
#define L_OFF   35143680

// ws float offsets
#define WS_WMT   0        // [64][32]  WmT[j*32+i] = sig(cm)-sig(pol)
#define WS_WL    2048     // [32][64]  Wl[i*64+j]  = sig(cm)
#define WS_SUMP  4096     // [32]      SUMP[i] = sum_j sig(pol[i][j])
#define WS_W1T   4128     // [128][128] w1T[n*128+m] = w1[m][n]
#define WS_W2T   20512    // [128][64]  w2T[m*64+j]  = w2[j][m]
#define WS_LPART 28704    // [256]
#define WS_SS    28960    // [16384]
#define WS_PWT   45344    // [2048][64] pwT[k*64+j] = prop_w[j][k]
#define WS_ET    176416   // [64][2048] eT[j*2048+d] = emb_w[d][j]
// total = 307488 floats (~1.2 MB)

__device__ __forceinline__ float sigf(float z) { return 1.0f / (1.0f + __expf(-z)); }

// ---------------- K0: weight pre-transforms ----------------
__global__ __launch_bounds__(256) void k0_prep(const float* __restrict__ cm, const float* __restrict__ pol,
                                               const float* __restrict__ w1, const float* __restrict__ w2,
                                               const float* __restrict__ pw, const float* __restrict__ ew,
                                               float* __restrict__ ws) {
  int gid = blockIdx.x * 256 + threadIdx.x;
  int stride = gridDim.x * 256;
  for (int idx = gid; idx < NC * NP; idx += stride) {
    int i = idx >> 6, j = idx & 63;
    float w = sigf(cm[idx]);
    float p = sigf(pol[idx]);
    ws[WS_WL + idx] = w;
    ws[WS_WMT + j * 32 + i] = w - p;
  }
  for (int idx = gid; idx < 128 * 128; idx += stride) {
    int n = idx >> 7, m = idx & 127;
    ws[WS_W1T + idx] = w1[m * 128 + n];
  }
  for (int idx = gid; idx < 128 * 64; idx += stride) {
    int m = idx >> 6, j = idx & 63;
    ws[WS_W2T + idx] = w2[j * 128 + m];
  }
  for (int idx = gid; idx < D * NP; idx += stride) {
    int k = idx >> 6, j = idx & 63;
    ws[WS_PWT + idx] = pw[j * D + k];
  }
  for (int idx = gid; idx < NP * D; idx += stride) {
    int j = idx >> 11, d = idx & 2047;
    ws[WS_ET + idx] = ew[d * NP + j];
  }
  if (gid < NC) {
    float s = 0.f;
    for (int j = 0; j < NP; ++j) s += sigf(pol[gid * NP + j]);
    ws[WS_SUMP + gid] = s;
  }
}

// ---------------- K1: props0 = sigmoid(x @ prop_w.T + b) ----------------
// block = 64 tokens (lane = token), 4 waves split K (512 each), reduce in LDS.
__global__ __launch_bounds__(256) void k1_props(const float* __restrict__ x, const float* __restrict__ ws,
                                                const float* __restrict__ pb, float* __restrict__ props0) {
  __shared__ float XL[4][64][65];  // [wave][k within chunk][token]; reused as ACC
  int tid = threadIdx.x, lane = tid & 63, wu = tid >> 6;
  int wuR = __builtin_amdgcn_readfirstlane(wu);
  int t0 = blockIdx.x * 64;
  const float* pwT = ws + WS_PWT;

  float acc[64];
#pragma unroll
  for (int j = 0; j < 64; ++j) acc[j] = 0.f;

  int dq = lane >> 4, trow = lane & 15;
  for (int c = 0; c < 8; ++c) {
    int kbase = 512 * wu + 64 * c;
    // stage own slice: x[t0..t0+63][kbase..kbase+63] -> XL[wu][k][t] (transposed)
    for (int tb = 0; tb < 4; ++tb) {
      int t = trow + 16 * tb;
#pragma unroll
      for (int i = 0; i < 4; ++i) {
        const float4 v = *(const float4*)&x[(size_t)(t0 + t) * D + kbase + (dq + 4 * i) * 4];
        int kk = (dq + 4 * i) * 4;
        XL[wu][kk + 0][t] = v.x; XL[wu][kk + 1][t] = v.y;
        XL[wu][kk + 2][t] = v.z; XL[wu][kk + 3][t] = v.w;
      }
    }
    __syncthreads();
    int kb = 512 * wuR + 64 * c;
    for (int kk = 0; kk < 64; ++kk) {
      float xk = XL[wu][kk][lane];
      const float* wr = &pwT[(size_t)(kb + kk) * 64];
#pragma unroll
      for (int j = 0; j < 64; ++j) acc[j] = fmaf(wr[j], xk, acc[j]);
    }
    __syncthreads();
  }

  // cross-wave K reduction: reuse XL memory as ACC[w][j][t] (each wave writes own slice)
  float* A = &XL[0][0][0];
#pragma unroll
  for (int j = 0; j < 64; ++j) A[wu * 4160 + j * 65 + lane] = acc[j];
  __syncthreads();
  for (int jj = 0; jj < 16; ++jj) {
    int j = 16 * wuR + jj;
    float s = A[0 * 4160 + j * 65 + lane] + A[1 * 4160 + j * 65 + lane] +
              A[2 * 4160 + j * 65 + lane] + A[3 * 4160 + j * 65 + lane];
    s += pb[j];
    props0[(size_t)(t0 + lane) * 64 + j] = sigf(s);
  }
}

// ---------------- K2: 3 correction iterations + sat/cons/loss ----------------
__global__ __launch_bounds__(256) void k2_iter(const float* __restrict__ ws, const float* __restrict__ b1,
                                               const float* __restrict__ b2, const float* __restrict__ cw,
                                               const float* __restrict__ cb, float* __restrict__ out,
                                               float* __restrict__ lpart) {
  __shared__ float H[128][64];   // h = [props(0..63); viol_signal(64..127)], column = token
  __shared__ float H2[128][64];
  __shared__ float SATs[32][64];
  int tid = threadIdx.x, lane = tid & 63, wu = tid >> 6;
  int wuR = __builtin_amdgcn_readfirstlane(wu);
  int t0 = blockIdx.x * 64;
  const float* WmT = ws + WS_WMT;
  const float* Wl = ws + WS_WL;
  const float* SUMP = ws + WS_SUMP;
  const float* w1T = ws + WS_W1T;
  const float* w2T = ws + WS_W2T;
  const float* props0 = out + P_OFF;

  // init H p-part (coalesced: each wave reads full 64-wide rows)
  for (int r = 0; r < 16; ++r) {
    int j = tid & 63, t = (tid >> 6) + 4 * r;
    H[j][t] = props0[(size_t)(t0 + t) * 64 + j];
  }
  __syncthreads();

  for (int it = 0; it < 4; ++it) {
    // satisfaction: sat_i = (sum_j p_j*(W-P)[i][j] + SUMP[i]) / 64
    float sacc[8];
#pragma unroll
    for (int ii = 0; ii < 8; ++ii) sacc[ii] = 0.f;
    for (int j = 0; j < 64; ++j) {
      float pj = H[j][lane];
      const float* wr = &WmT[j * 32 + 8 * wuR];
#pragma unroll
      for (int ii = 0; ii < 8; ++ii) sacc[ii] = fmaf(wr[ii], pj, sacc[ii]);
    }
#pragma unroll
    for (int ii = 0; ii < 8; ++ii) {
      int i = 8 * wuR + ii;
      SATs[i][lane] = (sacc[ii] + SUMP[i]) * (1.0f / 64.0f);
    }
    __syncthreads();
    if (it == 3) break;

    // viol_signal_j = (sum_i (1-sat_i) * W[i][j]) / (32 + 1e-6)
    float vacc[16];
#pragma unroll
    for (int jj = 0; jj < 16; ++jj) vacc[jj] = 0.f;
    for (int i = 0; i < 32; ++i) {
      float vi = 1.0f - SATs[i][lane];
      const float* wr = &Wl[i * 64 + 16 * wuR];
#pragma unroll
      for (int jj = 0; jj < 16; ++jj) vacc[jj] = fmaf(wr[jj], vi, vacc[jj]);
    }
#pragma unroll
    for (int jj = 0; jj < 16; ++jj)
      H[64 + 16 * wuR + jj][lane] = vacc[jj] * (1.0f / (32.0f + 1e-6f));
    __syncthreads();

    // h2 = gelu(corr_w1 @ h + b1), exact gelu
    float hacc[32];
#pragma unroll
    for (int mm = 0; mm < 32; ++mm) hacc[mm] = 0.f;
    for (int n = 0; n < 128; ++n) {
      float hn = H[n][lane];
      const float* wr = &w1T[n * 128 + 32 * wuR];
#pragma unroll
      for (int mm = 0; mm < 32; ++mm) hacc[mm] = fmaf(wr[mm], hn, hacc[mm]);
    }
#pragma unroll
    for (int mm = 0; mm < 32; ++mm) {
      int m = 32 * wuR + mm;
      float v = hacc[mm] + b1[m];
      H2[m][lane] = 0.5f * v * (1.0f + erff(v * 0.70710678118654752f));
    }
    __syncthreads();

    // props = sigmoid(corr_w2 @ h2 + b2)
    float pacc[16];
#pragma unroll
    for (int jj = 0; jj < 16; ++jj) pacc[jj] = 0.f;
    for (int m = 0; m < 128; ++m) {
      float hm = H2[m][lane];
      const float* wr = &w2T[m * 64 + 16 * wuR];
#pragma unroll
      for (int jj = 0; jj < 16; ++jj) pacc[jj] = fmaf(wr[jj], hm, pacc[jj]);
    }
#pragma unroll
    for (int jj = 0; jj < 16; ++jj) {
      int j = 16 * wuR + jj;
      H[j][lane] = sigf(pacc[jj] + b2[j]);
    }
    __syncthreads();
  }

  // outputs: props [t][j], sat [t][i] (coalesced f4 gathers from LDS)
  int tt = tid >> 2, cc = tid & 3;
  for (int r = 0; r < 4; ++r) {
    int j = cc * 4 + 16 * r;
    float4 v = make_float4(H[j][tt], H[j + 1][tt], H[j + 2][tt], H[j + 3][tt]);
    *(float4*)&out[P_OFF + (size_t)(t0 + tt) * 64 + j] = v;
  }
  for (int r = 0; r < 2; ++r) {
    int i = cc * 4 + 16 * r;
    float4 v = make_float4(SATs[i][tt], SATs[i + 1][tt], SATs[i + 2][tt], SATs[i + 3][tt]);
    *(float4*)&out[S_OFF + (size_t)(t0 + tt) * 32 + i] = v;
  }
  // consistency + loss partial (wave 0)
  if (wu == 0) {
    float a = 0.f, ssum = 0.f;
    for (int i = 0; i < 32; ++i) {
      float s = SATs[i][lane];
      a = fmaf(cw[i], s, a);
      ssum += s;
    }
    out[C_OFF + t0 + lane] = sigf(a + cb[0]);
    float v = 32.0f - ssum;  // sum_i (1 - sat_i) for this token
    for (int o = 32; o > 0; o >>= 1) v += __shfl_down(v, o);
    if (lane == 0) lpart[blockIdx.x] = v;
  }
}

// ---------------- K3: y_pre = x + (props@emb_w.T + emb_b)*cons; ss = sum y^2 ----------------
__global__ __launch_bounds__(256) void k3_emb(const float* __restrict__ x, const float* __restrict__ ws,
                                              const float* __restrict__ eb, float* __restrict__ out,
                                              float* __restrict__ ssOut) {
  __shared__ float XL[4][64][65];  // [wave][d within chunk][token]
  __shared__ float PL[64][65];     // props [j][token]
  __shared__ float SS[4][64];
  int tid = threadIdx.x, lane = tid & 63, wu = tid >> 6;
  int wuR = __builtin_amdgcn_readfirstlane(wu);
  int t0 = blockIdx.x * 64;
  const float* eT = ws + WS_ET;
  const float* propsf = out + P_OFF;

  for (int r = 0; r < 16; ++r) {
    int j = tid & 63, t = (tid >> 6) + 4 * r;
    PL[j][t] = propsf[(size_t)(t0 + t) * 64 + j];
  }
  float cons = out[C_OFF + t0 + lane];
  __syncthreads();

  float ss = 0.f;
  int dq = lane >> 4, trow = lane & 15;
  for (int c = 0; c < 8; ++c) {
    int dbase_v = 512 * wu + 64 * c;
    // stage own x slice (transposed)
    for (int tb = 0; tb < 4; ++tb) {
      int t = trow + 16 * tb;
#pragma unroll
      for (int i = 0; i < 4; ++i) {
        const float4 v = *(const float4*)&x[(size_t)(t0 + t) * D + dbase_v + (dq + 4 * i) * 4];
        int kk = (dq + 4 * i) * 4;
        XL[wu][kk + 0][t] = v.x; XL[wu][kk + 1][t] = v.y;
        XL[wu][kk + 2][t] = v.z; XL[wu][kk + 3][t] = v.w;
      }
    }
    __syncthreads();
    int dbase = 512 * wuR + 64 * c;
    float acc[64];
#pragma unroll
    for (int dd = 0; dd < 64; ++dd) acc[dd] = 0.f;
    for (int j = 0; j < 64; ++j) {
      float pj = PL[j][lane];
      const float* wr = &eT[(size_t)j * D + dbase];
#pragma unroll
      for (int dd = 0; dd < 64; ++dd) acc[dd] = fmaf(wr[dd], pj, acc[dd]);
    }
    // y_pre = x + (sym + emb_b)*cons ; accumulate ss; write back into XL
#pragma unroll
    for (int dd = 0; dd < 64; ++dd) {
      float yv = XL[wu][dd][lane] + (acc[dd] + eb[dbase + dd]) * cons;
      ss = fmaf(yv, yv, ss);
      XL[wu][dd][lane] = yv;
    }
    __syncthreads();
    // dump own slice to y (coalesced)
    for (int tb = 0; tb < 4; ++tb) {
      int t = trow + 16 * tb;
#pragma unroll
      for (int i = 0; i < 4; ++i) {
        int kk = (dq + 4 * i) * 4;
        float4 v = make_float4(XL[wu][kk][t], XL[wu][kk + 1][t], XL[wu][kk + 2][t], XL[wu][kk + 3][t]);
        *(float4*)&out[Y_OFF + (size_t)(t0 + t) * D + dbase_v + kk] = v;
      }
    }
    __syncthreads();
  }
  SS[wu][lane] = ss;
  __syncthreads();
  if (wu == 0)
    ssOut[t0 + lane] = SS[0][lane] + SS[1][lane] + SS[2][lane] + SS[3][lane];
}

// ---------------- K4: loss reduce ----------------
__global__ __launch_bounds__(256) void k4_loss(const float* __restrict__ lpart, float* __restrict__ loss) {
  __shared__ float w[4];
  float v = lpart[threadIdx.x];
  for (int o = 32; o > 0; o >>= 1) v += __shfl_down(v, o);
  if ((threadIdx.x & 63) == 0) w[threadIdx.x >> 6] = v;
  __syncthreads();
  if (threadIdx.x == 0)
    loss[0] = (w[0] + w[1] + w[2] + w[3]) * (1.0f / (16384.0f * 32.0f));
}

// ---------------- K5: RMSNorm rescale in place ----------------
__global__ __launch_bounds__(256) void k5_norm(float* __restrict__ y, const float* __restrict__ ssbuf,
                                               const float* __restrict__ nw) {
  int t = blockIdx.x, tid = threadIdx.x;
  float sc = rsqrtf(ssbuf[t] * (1.0f / 2048.0f) + 1e-6f);
#pragma unroll
  for (int r = 0; r < 2; ++r) {
    int d = (tid + 256 * r) * 4;
    float4 v = *(float4*)&y[(size_t)t * D + d];
    const float4 w = *(const float4*)&nw[d];
    v.x *= sc * w.x; v.y *= sc * w.y; v.z *= sc * w.z; v.w *= sc * w.w;
    *(float4*)&y[(size_t)t * D + d] = v;
  }
}

extern "C" void kernel_launch(void* const* d_in, const int* in_sizes, int n_in,
                              void* d_out, int out_size, void* d_ws, size_t ws_size,
                              hipStream_t stream) {
  (void)in_sizes; (void)n_in; (void)out_size; (void)ws_size;
  const float* x   = (const float*)d_in[0];
  const float* pw  = (const float*)d_in[1];
  const float* pb  = (const float*)d_in[2];
  const float* cm  = (const float*)d_in[3];
  const float* pol = (const float*)d_in[4];
  const float* w1  = (const float*)d_in[5];
  const float* b1  = (const float*)d_in[6];
  const float* w2  = (const float*)d_in[7];
  const float* b2  = (const float*)d_in[8];
  const float* cw  = (const float*)d_in[9];
  const float* cb  = (const float*)d_in[10];
  const float* ew  = (const float*)d_in[11];
  const float* eb  = (const float*)d_in[12];
  const float* nw  = (const float*)d_in[13];
  float* out = (float*)d_out;
  float* ws  = (float*)d_ws;

  hipLaunchKernelGGL(k0_prep, dim3(64), dim3(256), 0, stream, cm, pol, w1, w2, pw, ew, ws);
  hipLaunchKernelGGL(k1_props, dim3(T / 64), dim3(256), 0, stream, x, ws, pb, out + P_OFF);
  hipLaunchKernelGGL(k2_iter, dim3(T / 64), dim3(256), 0, stream, ws, b1, b2, cw, cb, out, ws + WS_LPART);
  hipLaunchKernelGGL(k4_loss, dim3(1), dim3(256), 0, stream, ws + WS_LPART, out + L_OFF);
  hipLaunchKernelGGL(k3_emb, dim3(T / 64), dim3(256), 0, stream, x, ws, eb, out, ws + WS_SS);
  hipLaunchKernelGGL(k5_norm, dim3(T), dim3(256), 0, stream, out, ws + WS_SS, nw);
}

// Round 2
// 372.663 us; speedup vs baseline: 2.4446x; 2.4446x over previous
//
#include <hip/hip_runtime.h>
#include <hip/hip_bf16.h>
#include <cstdint>

#define D     2048
#define NP    64
#define NC    32
#define T     16384

// d_out float offsets (y, props, satisfaction, consistency, loss)
#define Y_OFF   0
#define P_OFF   33554432
#define S_OFF   34603008
#define C_OFF   35127296
#define L_OFF   35143680

// ws float offsets
#define WS_WMT   0        // [64][32]  WmT[j*32+i] = sig(cm)-sig(pol)
#define WS_WL    2048     // [32][64]  Wl[i*64+j]  = sig(cm)
#define WS_SUMP  4096     // [32]      SUMP[i] = sum_j sig(pol[i][j])
#define WS_W1T   4128     // [128][128] w1T[n*128+m] = w1[m][n]
#define WS_W2T   20512    // [128][64]  w2T[m*64+j]  = w2[j][m]
#define WS_LPART 28704    // [256]
#define WS_PWT   45344    // [2048][64] pwT[k*64+j] = prop_w[j][k]
#define WS_ET    176416   // [64][2048] eT[j*2048+d] = emb_w[d][j]
#define WS_SSP   307488   // [8][16384] per-dgroup partial sum of y^2
// total = 438560 floats (~1.75 MB)

__device__ __forceinline__ float sigf(float z) { return 1.0f / (1.0f + __expf(-z)); }

// ---------------- K0: weight pre-transforms ----------------
__global__ __launch_bounds__(256) void k0_prep(const float* __restrict__ cm, const float* __restrict__ pol,
                                               const float* __restrict__ w1, const float* __restrict__ w2,
                                               const float* __restrict__ pw, const float* __restrict__ ew,
                                               float* __restrict__ ws) {
  int gid = blockIdx.x * 256 + threadIdx.x;
  int stride = gridDim.x * 256;
  for (int idx = gid; idx < NC * NP; idx += stride) {
    int i = idx >> 6, j = idx & 63;
    float w = sigf(cm[idx]);
    float p = sigf(pol[idx]);
    ws[WS_WL + idx] = w;
    ws[WS_WMT + j * 32 + i] = w - p;
  }
  for (int idx = gid; idx < 128 * 128; idx += stride) {
    int n = idx >> 7, m = idx & 127;
    ws[WS_W1T + idx] = w1[m * 128 + n];
  }
  for (int idx = gid; idx < 128 * 64; idx += stride) {
    int m = idx >> 6, j = idx & 63;
    ws[WS_W2T + idx] = w2[j * 128 + m];
  }
  for (int idx = gid; idx < D * NP; idx += stride) {
    int k = idx >> 6, j = idx & 63;
    ws[WS_PWT + idx] = pw[j * D + k];
  }
  for (int idx = gid; idx < NP * D; idx += stride) {
    int j = idx >> 11, d = idx & 2047;
    ws[WS_ET + idx] = ew[d * NP + j];
  }
  if (gid < NC) {
    float s = 0.f;
    for (int j = 0; j < NP; ++j) s += sigf(pol[gid * NP + j]);
    ws[WS_SUMP + gid] = s;
  }
}

// ---------------- K1: partial[kb2][t][j] = sum_{k in half kb2} x[t][k]*pwT[k][j] ----------------
// grid 512 = 256 token-blocks x 2 K-halves. 64 tokens/block (lane=token), 4 waves split 1024 K.
// LDS slices are wave-private: no barriers in the main loop.
__global__ __launch_bounds__(256) void k1_props(const float* __restrict__ x, const float* __restrict__ ws,
                                                float* __restrict__ part) {
  __shared__ float XL[4][64][65];  // [wave][k within chunk][token]; reused for reductions
  int tid = threadIdx.x, lane = tid & 63, wu = tid >> 6;
  int wuR = __builtin_amdgcn_readfirstlane(wu);
  int t0 = (blockIdx.x >> 1) * 64;
  int kb2 = blockIdx.x & 1;
  const float* pwT = ws + WS_PWT;

  float acc[64];
#pragma unroll
  for (int j = 0; j < 64; ++j) acc[j] = 0.f;

  int dq = lane >> 4, trow = lane & 15;
  for (int c = 0; c < 4; ++c) {
    int kbase = kb2 * 1024 + 256 * wu + 64 * c;
    // stage own slice: x[t0..t0+63][kbase..kbase+63] -> XL[wu][k][t] (transposed)
    for (int tb = 0; tb < 4; ++tb) {
      int t = trow + 16 * tb;
#pragma unroll
      for (int i = 0; i < 4; ++i) {
        const float4 v = *(const float4*)&x[(size_t)(t0 + t) * D + kbase + (dq + 4 * i) * 4];
        int kk = (dq + 4 * i) * 4;
        XL[wu][kk + 0][t] = v.x; XL[wu][kk + 1][t] = v.y;
        XL[wu][kk + 2][t] = v.z; XL[wu][kk + 3][t] = v.w;
      }
    }
    // no __syncthreads: XL[wu] is private to this wave; in-wave DS ordering suffices
    int kbG = kb2 * 1024 + 256 * wuR + 64 * c;
    for (int kk = 0; kk < 64; ++kk) {
      float xk = XL[wu][kk][lane];
      const float* wr = &pwT[(size_t)(kbG + kk) * 64];
#pragma unroll
      for (int j = 0; j < 64; ++j) acc[j] = fmaf(wr[j], xk, acc[j]);
    }
  }

  // cross-wave K reduction in LDS (reuse XL as A[w][j][t])
  float* A = &XL[0][0][0];
#pragma unroll
  for (int j = 0; j < 64; ++j) A[wu * 4160 + j * 65 + lane] = acc[j];
  __syncthreads();
  for (int jj = 0; jj < 16; ++jj) {
    int j = 16 * wuR + jj;
    float s = A[0 * 4160 + j * 65 + lane] + A[1 * 4160 + j * 65 + lane] +
              A[2 * 4160 + j * 65 + lane] + A[3 * 4160 + j * 65 + lane];
    A[j * 65 + lane] = s;  // safe: this thread just consumed this slot
  }
  __syncthreads();
  // coalesced store of the partial (64-float rows)
  for (int r = 0; r < 16; ++r) {
    int t = (tid >> 6) + 4 * r, j = tid & 63;
    part[(size_t)kb2 * 1048576 + (size_t)(t0 + t) * 64 + j] = A[j * 65 + t];
  }
}

// ---------------- K2: init from partials + 3 correction iterations + sat/cons/loss ----------------
// block = 512 threads (8 waves), 64 tokens (lane = token), waves split outputs.
__global__ __launch_bounds__(512) void k2_iter(const float* __restrict__ ws, const float* __restrict__ pb,
                                               const float* __restrict__ b1, const float* __restrict__ b2,
                                               const float* __restrict__ cw, const float* __restrict__ cb,
                                               const float* __restrict__ part, float* __restrict__ out,
                                               float* __restrict__ lpart) {
  __shared__ float H[128][64];   // h = [props(0..63); viol_signal(64..127)], column = token
  __shared__ float H2[128][64];
  __shared__ float SATs[32][64];
  int tid = threadIdx.x, lane = tid & 63, wu = tid >> 6;  // wu in [0,8)
  int wuR = __builtin_amdgcn_readfirstlane(wu);
  int t0 = blockIdx.x * 64;
  const float* WmT = ws + WS_WMT;
  const float* Wl = ws + WS_WL;
  const float* SUMP = ws + WS_SUMP;
  const float* w1T = ws + WS_W1T;
  const float* w2T = ws + WS_W2T;

  // init H p-part from the two K-partials (+bias, sigmoid); coalesced rows
  for (int r = 0; r < 8; ++r) {
    int j = tid & 63, t = (tid >> 6) + 8 * r;
    size_t idx = (size_t)(t0 + t) * 64 + j;
    H[j][t] = sigf(part[idx] + part[1048576 + idx] + pb[j]);
  }
  __syncthreads();

  for (int it = 0; it < 4; ++it) {
    // satisfaction: sat_i = (sum_j p_j*(W-P)[i][j] + SUMP[i]) / 64   (4 i per wave)
    float sacc[4];
#pragma unroll
    for (int ii = 0; ii < 4; ++ii) sacc[ii] = 0.f;
    for (int j = 0; j < 64; ++j) {
      float pj = H[j][lane];
      const float* wr = &WmT[j * 32 + 4 * wuR];
#pragma unroll
      for (int ii = 0; ii < 4; ++ii) sacc[ii] = fmaf(wr[ii], pj, sacc[ii]);
    }
#pragma unroll
    for (int ii = 0; ii < 4; ++ii) {
      int i = 4 * wuR + ii;
      SATs[i][lane] = (sacc[ii] + SUMP[i]) * (1.0f / 64.0f);
    }
    __syncthreads();
    if (it == 3) break;

    // viol_signal_j = (sum_i (1-sat_i) * W[i][j]) / (32 + 1e-6)   (8 j per wave)
    float vacc[8];
#pragma unroll
    for (int jj = 0; jj < 8; ++jj) vacc[jj] = 0.f;
    for (int i = 0; i < 32; ++i) {
      float vi = 1.0f - SATs[i][lane];
      const float* wr = &Wl[i * 64 + 8 * wuR];
#pragma unroll
      for (int jj = 0; jj < 8; ++jj) vacc[jj] = fmaf(wr[jj], vi, vacc[jj]);
    }
#pragma unroll
    for (int jj = 0; jj < 8; ++jj)
      H[64 + 8 * wuR + jj][lane] = vacc[jj] * (1.0f / (32.0f + 1e-6f));
    __syncthreads();

    // h2 = gelu(corr_w1 @ h + b1), exact gelu   (16 m per wave)
    float hacc[16];
#pragma unroll
    for (int mm = 0; mm < 16; ++mm) hacc[mm] = 0.f;
    for (int n = 0; n < 128; ++n) {
      float hn = H[n][lane];
      const float* wr = &w1T[n * 128 + 16 * wuR];
#pragma unroll
      for (int mm = 0; mm < 16; ++mm) hacc[mm] = fmaf(wr[mm], hn, hacc[mm]);
    }
#pragma unroll
    for (int mm = 0; mm < 16; ++mm) {
      int m = 16 * wuR + mm;
      float v = hacc[mm] + b1[m];
      H2[m][lane] = 0.5f * v * (1.0f + erff(v * 0.70710678118654752f));
    }
    __syncthreads();

    // props = sigmoid(corr_w2 @ h2 + b2)   (8 j per wave)
    float pacc[8];
#pragma unroll
    for (int jj = 0; jj < 8; ++jj) pacc[jj] = 0.f;
    for (int m = 0; m < 128; ++m) {
      float hm = H2[m][lane];
      const float* wr = &w2T[m * 64 + 8 * wuR];
#pragma unroll
      for (int jj = 0; jj < 8; ++jj) pacc[jj] = fmaf(wr[jj], hm, pacc[jj]);
    }
#pragma unroll
    for (int jj = 0; jj < 8; ++jj) {
      int j = 8 * wuR + jj;
      H[j][lane] = sigf(pacc[jj] + b2[j]);
    }
    __syncthreads();
  }

  // outputs: props [t][j] (2 f4/thread), sat [t][i] (1 f4/thread)
  int tt = tid >> 3, cc = tid & 7;
#pragma unroll
  for (int r = 0; r < 2; ++r) {
    int j = 4 * (cc + 8 * r);
    float4 v = make_float4(H[j][tt], H[j + 1][tt], H[j + 2][tt], H[j + 3][tt]);
    *(float4*)&out[P_OFF + (size_t)(t0 + tt) * 64 + j] = v;
  }
  {
    int i = 4 * cc;
    float4 v = make_float4(SATs[i][tt], SATs[i + 1][tt], SATs[i + 2][tt], SATs[i + 3][tt]);
    *(float4*)&out[S_OFF + (size_t)(t0 + tt) * 32 + i] = v;
  }
  // consistency + loss partial (wave 0, lane = token)
  if (wu == 0) {
    float a = 0.f, ssum = 0.f;
    for (int i = 0; i < 32; ++i) {
      float s = SATs[i][lane];
      a = fmaf(cw[i], s, a);
      ssum += s;
    }
    out[C_OFF + t0 + lane] = sigf(a + cb[0]);
    float v = 32.0f - ssum;
    for (int o = 32; o > 0; o >>= 1) v += __shfl_down(v, o);
    if (lane == 0) lpart[blockIdx.x] = v;
  }
}

// ---------------- K3: y_pre = x + (props@emb_w.T + emb_b)*cons; ssPart[dgrp][t] = partial sum y^2 ----
// grid 4096 = 512 token-groups (32 tokens) x 8 d-groups (256 d). block 256 = 4 waves.
// Wave wu owns 8 tokens; lane owns one float4 of d. emb tile staged in LDS [64][256] (64KB).
__global__ __launch_bounds__(256) void k3_emb(const float* __restrict__ x, const float* __restrict__ ws,
                                              const float* __restrict__ eb, float* __restrict__ out,
                                              float* __restrict__ ssPart) {
  __shared__ float EL[64][256];
  int tid = threadIdx.x, lane = tid & 63, wu = tid >> 6;
  int wuR = __builtin_amdgcn_readfirstlane(wu);
  int tgrp = blockIdx.x & 511, dgrp = blockIdx.x >> 9;
  int dbase = dgrp * 256;
  const float* eT = ws + WS_ET;
  const float* props = out + P_OFF;

  // stage emb tile: EL[j][d] = emb_w[dbase+d][j]  (coalesced f4 rows)
  for (int r = 0; r < 16; ++r) {
    int idx = r * 256 + tid;
    int j = idx >> 6, d4 = idx & 63;
    *(float4*)&EL[j][4 * d4] = *(const float4*)&eT[(size_t)j * D + dbase + 4 * d4];
  }
  __syncthreads();

  int t0 = tgrp * 32 + wuR * 8;
  float4 acc[8];
#pragma unroll
  for (int ti = 0; ti < 8; ++ti) acc[ti] = make_float4(0.f, 0.f, 0.f, 0.f);

  for (int jc = 0; jc < 16; ++jc) {
    float4 e0 = *(const float4*)&EL[4 * jc + 0][4 * lane];
    float4 e1 = *(const float4*)&EL[4 * jc + 1][4 * lane];
    float4 e2 = *(const float4*)&EL[4 * jc + 2][4 * lane];
    float4 e3 = *(const float4*)&EL[4 * jc + 3][4 * lane];
#pragma unroll
    for (int ti = 0; ti < 8; ++ti) {
      const float4 p = *(const float4*)&props[(size_t)(t0 + ti) * 64 + 4 * jc];  // wave-uniform
      acc[ti].x = fmaf(p.x, e0.x, acc[ti].x); acc[ti].y = fmaf(p.x, e0.y, acc[ti].y);
      acc[ti].z = fmaf(p.x, e0.z, acc[ti].z); acc[ti].w = fmaf(p.x, e0.w, acc[ti].w);
      acc[ti].x = fmaf(p.y, e1.x, acc[ti].x); acc[ti].y = fmaf(p.y, e1.y, acc[ti].y);
      acc[ti].z = fmaf(p.y, e1.z, acc[ti].z); acc[ti].w = fmaf(p.y, e1.w, acc[ti].w);
      acc[ti].x = fmaf(p.z, e2.x, acc[ti].x); acc[ti].y = fmaf(p.z, e2.y, acc[ti].y);
      acc[ti].z = fmaf(p.z, e2.z, acc[ti].z); acc[ti].w = fmaf(p.z, e2.w, acc[ti].w);
      acc[ti].x = fmaf(p.w, e3.x, acc[ti].x); acc[ti].y = fmaf(p.w, e3.y, acc[ti].y);
      acc[ti].z = fmaf(p.w, e3.z, acc[ti].z); acc[ti].w = fmaf(p.w, e3.w, acc[ti].w);
    }
  }

  const float4 ebv = *(const float4*)&eb[dbase + 4 * lane];
#pragma unroll
  for (int ti = 0; ti < 8; ++ti) {
    int t = t0 + ti;
    float cons = out[C_OFF + t];  // wave-uniform
    float4 xv = *(const float4*)&x[(size_t)t * D + dbase + 4 * lane];
    float4 yv;
    yv.x = fmaf(acc[ti].x + ebv.x, cons, xv.x);
    yv.y = fmaf(acc[ti].y + ebv.y, cons, xv.y);
    yv.z = fmaf(acc[ti].z + ebv.z, cons, xv.z);
    yv.w = fmaf(acc[ti].w + ebv.w, cons, xv.w);
    *(float4*)&out[Y_OFF + (size_t)t * D + dbase + 4 * lane] = yv;
    float s = yv.x * yv.x + yv.y * yv.y + yv.z * yv.z + yv.w * yv.w;
#pragma unroll
    for (int m = 32; m >= 1; m >>= 1) s += __shfl_xor(s, m, 64);
    if (lane == 0) ssPart[dgrp * 16384 + t] = s;
  }
}

// ---------------- K4: loss reduce ----------------
__global__ __launch_bounds__(256) void k4_loss(const float* __restrict__ lpart, float* __restrict__ loss) {
  __shared__ float w[4];
  float v = lpart[threadIdx.x];
  for (int o = 32; o > 0; o >>= 1) v += __shfl_down(v, o);
  if ((threadIdx.x & 63) == 0) w[threadIdx.x >> 6] = v;
  __syncthreads();
  if (threadIdx.x == 0)
    loss[0] = (w[0] + w[1] + w[2] + w[3]) * (1.0f / (16384.0f * 32.0f));
}

// ---------------- K5: RMSNorm rescale in place ----------------
__global__ __launch_bounds__(256) void k5_norm(float* __restrict__ y, const float* __restrict__ ssPart,
                                               const float* __restrict__ nw) {
  int t = blockIdx.x, tid = threadIdx.x;
  float ss = 0.f;
#pragma unroll
  for (int g = 0; g < 8; ++g) ss += ssPart[g * 16384 + t];
  float sc = rsqrtf(ss * (1.0f / 2048.0f) + 1e-6f);
#pragma unroll
  for (int r = 0; r < 2; ++r) {
    int d = (tid + 256 * r) * 4;
    float4 v = *(float4*)&y[(size_t)t * D + d];
    const float4 w = *(const float4*)&nw[d];
    v.x *= sc * w.x; v.y *= sc * w.y; v.z *= sc * w.z; v.w *= sc * w.w;
    *(float4*)&y[(size_t)t * D + d] = v;
  }
}

extern "C" void kernel_launch(void* const* d_in, const int* in_sizes, int n_in,
                              void* d_out, int out_size, void* d_ws, size_t ws_size,
                              hipStream_t stream) {
  (void)in_sizes; (void)n_in; (void)out_size; (void)ws_size;
  const float* x   = (const float*)d_in[0];
  const float* pw  = (const float*)d_in[1];
  const float* pb  = (const float*)d_in[2];
  const float* cm  = (const float*)d_in[3];
  const float* pol = (const float*)d_in[4];
  const float* w1  = (const float*)d_in[5];
  const float* b1  = (const float*)d_in[6];
  const float* w2  = (const float*)d_in[7];
  const float* b2  = (const float*)d_in[8];
  const float* cw  = (const float*)d_in[9];
  const float* cb  = (const float*)d_in[10];
  const float* ew  = (const float*)d_in[11];
  const float* eb  = (const float*)d_in[12];
  const float* nw  = (const float*)d_in[13];
  float* out = (float*)d_out;
  float* ws  = (float*)d_ws;

  hipLaunchKernelGGL(k0_prep, dim3(64), dim3(256), 0, stream, cm, pol, w1, w2, pw, ew, ws);
  // k1 writes K-split partials into the y region of d_out (dead until k3 overwrites it)
  hipLaunchKernelGGL(k1_props, dim3(512), dim3(256), 0, stream, x, ws, out + Y_OFF);
  hipLaunchKernelGGL(k2_iter, dim3(256), dim3(512), 0, stream, ws, pb, b1, b2, cw, cb,
                     out + Y_OFF, out, ws + WS_LPART);
  hipLaunchKernelGGL(k4_loss, dim3(1), dim3(256), 0, stream, ws + WS_LPART, out + L_OFF);
  hipLaunchKernelGGL(k3_emb, dim3(4096), dim3(256), 0, stream, x, ws, eb, out, ws + WS_SSP);
  hipLaunchKernelGGL(k5_norm, dim3(16384), dim3(256), 0, stream, out, ws + WS_SSP, nw);
}

// Round 3
// 293.383 us; speedup vs baseline: 3.1052x; 1.2702x over previous
//
#include <hip/hip_runtime.h>
#include <hip/hip_bf16.h>
#include <cstdint>

#define D     2048
#define NP    64
#define NC    32
#define T     16384

// d_out float offsets (y, props, satisfaction, consistency, loss)
#define Y_OFF   0
#define P_OFF   33554432
#define S_OFF   34603008
#define C_OFF   35127296
#define L_OFF   35143680

// ws float offsets
#define WS_WMT   0        // [64][32]  WmT[j*32+i] = sig(cm)-sig(pol)
#define WS_WL    2048     // [32][64]  Wl[i*64+j]  = sig(cm)
#define WS_SUMP  4096     // [32]      SUMP[i] = sum_j sig(pol[i][j])
#define WS_W1T   4128     // [128][128] w1T[n*128+m] = w1[m][n]
#define WS_W2T   20512    // [128][64]  w2T[m*64+j]  = w2[j][m]
#define WS_LPART 28704    // [256]
#define WS_PWF   28960    // bf16 frags [64 kc][4 jt][64 lane][8] = 131072 bf16 = 65536 f-words
#define WS_EF    94496    // bf16 frags [128 dt][2 kc][64 lane][8] = 131072 bf16
#define WS_SSP   160032   // [4][16384] partial sum y^2
// end 225568 floats (~0.9 MB)

typedef short short8 __attribute__((ext_vector_type(8)));
typedef float f32x4 __attribute__((ext_vector_type(4)));

__device__ __forceinline__ float sigf(float z) { return 1.0f / (1.0f + __expf(-z)); }
__device__ __forceinline__ short f2bf(float f) {
  unsigned u = __float_as_uint(f);
  return (short)((u + 0x8000u) >> 16);   // round-half-up bf16
}

// ---------------- K0: weight pre-transforms + MFMA B-fragment packing ----------------
__global__ __launch_bounds__(256) void k0_prep(const float* __restrict__ cm, const float* __restrict__ pol,
                                               const float* __restrict__ w1, const float* __restrict__ w2,
                                               const float* __restrict__ pw, const float* __restrict__ ew,
                                               float* __restrict__ ws) {
  int gid = blockIdx.x * 256 + threadIdx.x;
  int stride = gridDim.x * 256;
  for (int idx = gid; idx < NC * NP; idx += stride) {
    int i = idx >> 6, j = idx & 63;
    float w = sigf(cm[idx]);
    float p = sigf(pol[idx]);
    ws[WS_WL + idx] = w;
    ws[WS_WMT + j * 32 + i] = w - p;
  }
  for (int idx = gid; idx < 128 * 128; idx += stride) {
    int n = idx >> 7, m = idx & 127;
    ws[WS_W1T + idx] = w1[m * 128 + n];
  }
  for (int idx = gid; idx < 128 * 64; idx += stride) {
    int m = idx >> 6, j = idx & 63;
    ws[WS_W2T + idx] = w2[j * 128 + m];
  }
  // pwF: B-frag for GEMM1. (kc,jt,lane,e) -> pw[j=16jt+(l&15)][k=32kc+8*(l>>4)+e]
  short* pwF = (short*)(ws + WS_PWF);
  for (int idx = gid; idx < 64 * 4 * 64; idx += stride) {
    int kc = idx >> 8, jt = (idx >> 6) & 3, l = idx & 63;
    int j = 16 * jt + (l & 15), k = 32 * kc + 8 * (l >> 4);
    const float* src = &pw[(size_t)j * D + k];
    short8 v;
#pragma unroll
    for (int e = 0; e < 8; ++e) v[e] = f2bf(src[e]);
    *(short8*)&pwF[idx * 8] = v;
  }
  // eF: B-frag for GEMM2. (dt,kc,lane,e) -> emb_w[d=16dt+(l&15)][j=32kc+8*(l>>4)+e]
  short* eF = (short*)(ws + WS_EF);
  for (int idx = gid; idx < 128 * 2 * 64; idx += stride) {
    int dt = idx >> 7, kc = (idx >> 6) & 1, l = idx & 63;
    int d = 16 * dt + (l & 15), j = 32 * kc + 8 * (l >> 4);
    const float* src = &ew[(size_t)d * NP + j];
    short8 v;
#pragma unroll
    for (int e = 0; e < 8; ++e) v[e] = f2bf(src[e]);
    *(short8*)&eF[idx * 8] = v;
  }
  if (gid < NC) {
    float s = 0.f;
    for (int j = 0; j < NP; ++j) s += sigf(pol[gid * NP + j]);
    ws[WS_SUMP + gid] = s;
  }
}

// ---------------- K1: props0 = sigmoid(x @ prop_w.T + pb) via MFMA ----------------
// grid 1024 (16 tokens/block), 4 waves = 4 j-tiles. No LDS.
__global__ __launch_bounds__(256) void k1_props(const float* __restrict__ x, const float* __restrict__ ws,
                                                const float* __restrict__ pb, float* __restrict__ props0) {
  int tid = threadIdx.x, lane = tid & 63;
  int jt = __builtin_amdgcn_readfirstlane(tid >> 6);
  int t0 = blockIdx.x * 16;
  int lr = lane & 15, lg = lane >> 4;
  const short* pwF = (const short*)(ws + WS_PWF);
  const float* xrow = x + (size_t)(t0 + lr) * D + 8 * lg;

  f32x4 acc = {0.f, 0.f, 0.f, 0.f};
  for (int kc = 0; kc < 64; ++kc) {
    const float* xp = xrow + 32 * kc;
    const float4 xa = *(const float4*)xp;
    const float4 xb = *(const float4*)(xp + 4);
    short8 a;
    a[0] = f2bf(xa.x); a[1] = f2bf(xa.y); a[2] = f2bf(xa.z); a[3] = f2bf(xa.w);
    a[4] = f2bf(xb.x); a[5] = f2bf(xb.y); a[6] = f2bf(xb.z); a[7] = f2bf(xb.w);
    const short8 b = *(const short8*)&pwF[((kc * 4 + jt) * 64 + lane) * 8];
    acc = __builtin_amdgcn_mfma_f32_16x16x32_bf16(a, b, acc, 0, 0, 0);
  }
  int j = 16 * jt + lr;
  float bj = pb[j];
#pragma unroll
  for (int r = 0; r < 4; ++r) {
    int t = t0 + 4 * lg + r;
    props0[(size_t)t * 64 + j] = sigf(acc[r] + bj);
  }
}

// ---------------- K2: 3 correction iterations + sat/cons/loss ----------------
// block = 512 threads (8 waves), 64 tokens (lane = token), waves split outputs.
__global__ __launch_bounds__(512) void k2_iter(const float* __restrict__ ws,
                                               const float* __restrict__ b1, const float* __restrict__ b2,
                                               const float* __restrict__ cw, const float* __restrict__ cb,
                                               const float* __restrict__ props0, float* __restrict__ out,
                                               float* __restrict__ lpart) {
  __shared__ float H[128][64];   // h = [props(0..63); viol_signal(64..127)], column = token
  __shared__ float H2[128][64];
  __shared__ float SATs[32][64];
  int tid = threadIdx.x, lane = tid & 63, wu = tid >> 6;  // wu in [0,8)
  int wuR = __builtin_amdgcn_readfirstlane(wu);
  int t0 = blockIdx.x * 64;
  const float* WmT = ws + WS_WMT;
  const float* Wl = ws + WS_WL;
  const float* SUMP = ws + WS_SUMP;
  const float* w1T = ws + WS_W1T;
  const float* w2T = ws + WS_W2T;

  // init H p-part (already sigmoided by k1); coalesced rows
  for (int r = 0; r < 8; ++r) {
    int j = tid & 63, t = (tid >> 6) + 8 * r;
    H[j][t] = props0[(size_t)(t0 + t) * 64 + j];
  }
  __syncthreads();

  for (int it = 0; it < 4; ++it) {
    // satisfaction: sat_i = (sum_j p_j*(W-P)[i][j] + SUMP[i]) / 64   (4 i per wave)
    float sacc[4];
#pragma unroll
    for (int ii = 0; ii < 4; ++ii) sacc[ii] = 0.f;
    for (int j = 0; j < 64; ++j) {
      float pj = H[j][lane];
      const float* wr = &WmT[j * 32 + 4 * wuR];
#pragma unroll
      for (int ii = 0; ii < 4; ++ii) sacc[ii] = fmaf(wr[ii], pj, sacc[ii]);
    }
#pragma unroll
    for (int ii = 0; ii < 4; ++ii) {
      int i = 4 * wuR + ii;
      SATs[i][lane] = (sacc[ii] + SUMP[i]) * (1.0f / 64.0f);
    }
    __syncthreads();
    if (it == 3) break;

    // viol_signal_j = (sum_i (1-sat_i) * W[i][j]) / (32 + 1e-6)   (8 j per wave)
    float vacc[8];
#pragma unroll
    for (int jj = 0; jj < 8; ++jj) vacc[jj] = 0.f;
    for (int i = 0; i < 32; ++i) {
      float vi = 1.0f - SATs[i][lane];
      const float* wr = &Wl[i * 64 + 8 * wuR];
#pragma unroll
      for (int jj = 0; jj < 8; ++jj) vacc[jj] = fmaf(wr[jj], vi, vacc[jj]);
    }
#pragma unroll
    for (int jj = 0; jj < 8; ++jj)
      H[64 + 8 * wuR + jj][lane] = vacc[jj] * (1.0f / (32.0f + 1e-6f));
    __syncthreads();

    // h2 = gelu(corr_w1 @ h + b1), exact gelu   (16 m per wave)
    float hacc[16];
#pragma unroll
    for (int mm = 0; mm < 16; ++mm) hacc[mm] = 0.f;
    for (int n = 0; n < 128; ++n) {
      float hn = H[n][lane];
      const float* wr = &w1T[n * 128 + 16 * wuR];
#pragma unroll
      for (int mm = 0; mm < 16; ++mm) hacc[mm] = fmaf(wr[mm], hn, hacc[mm]);
    }
#pragma unroll
    for (int mm = 0; mm < 16; ++mm) {
      int m = 16 * wuR + mm;
      float v = hacc[mm] + b1[m];
      H2[m][lane] = 0.5f * v * (1.0f + erff(v * 0.70710678118654752f));
    }
    __syncthreads();

    // props = sigmoid(corr_w2 @ h2 + b2)   (8 j per wave)
    float pacc[8];
#pragma unroll
    for (int jj = 0; jj < 8; ++jj) pacc[jj] = 0.f;
    for (int m = 0; m < 128; ++m) {
      float hm = H2[m][lane];
      const float* wr = &w2T[m * 64 + 8 * wuR];
#pragma unroll
      for (int jj = 0; jj < 8; ++jj) pacc[jj] = fmaf(wr[jj], hm, pacc[jj]);
    }
#pragma unroll
    for (int jj = 0; jj < 8; ++jj) {
      int j = 8 * wuR + jj;
      H[j][lane] = sigf(pacc[jj] + b2[j]);
    }
    __syncthreads();
  }

  // outputs: props [t][j] (2 f4/thread), sat [t][i] (1 f4/thread)
  int tt = tid >> 3, cc = tid & 7;
#pragma unroll
  for (int r = 0; r < 2; ++r) {
    int j = 4 * (cc + 8 * r);
    float4 v = make_float4(H[j][tt], H[j + 1][tt], H[j + 2][tt], H[j + 3][tt]);
    *(float4*)&out[P_OFF + (size_t)(t0 + tt) * 64 + j] = v;
  }
  {
    int i = 4 * cc;
    float4 v = make_float4(SATs[i][tt], SATs[i + 1][tt], SATs[i + 2][tt], SATs[i + 3][tt]);
    *(float4*)&out[S_OFF + (size_t)(t0 + tt) * 32 + i] = v;
  }
  // consistency + loss partial (wave 0, lane = token)
  if (wu == 0) {
    float a = 0.f, ssum = 0.f;
    for (int i = 0; i < 32; ++i) {
      float s = SATs[i][lane];
      a = fmaf(cw[i], s, a);
      ssum += s;
    }
    out[C_OFF + t0 + lane] = sigf(a + cb[0]);
    float v = 32.0f - ssum;
    for (int o = 32; o > 0; o >>= 1) v += __shfl_down(v, o);
    if (lane == 0) lpart[blockIdx.x] = v;
  }
}

// ---------------- K3: y_pre = x + (props@emb_w.T + eb)*cons via MFMA; ssPart ----------------
// grid 1024 (16 tokens/block), 4 waves = 4 d-quarters (512 d each). No LDS.
__global__ __launch_bounds__(256) void k3_emb(const float* __restrict__ x, const float* __restrict__ ws,
                                              const float* __restrict__ eb, float* __restrict__ out,
                                              float* __restrict__ ssPart) {
  int tid = threadIdx.x, lane = tid & 63;
  int dq = __builtin_amdgcn_readfirstlane(tid >> 6);
  int t0 = blockIdx.x * 16;
  int lr = lane & 15, lg = lane >> 4;
  const short* eF = (const short*)(ws + WS_EF);

  // A-frags from final props (fp32, row-major [t][64])
  const float* pr = out + P_OFF + (size_t)(t0 + lr) * 64 + 8 * lg;
  const float4 q0 = *(const float4*)pr;
  const float4 q1 = *(const float4*)(pr + 4);
  const float4 q2 = *(const float4*)(pr + 32);
  const float4 q3 = *(const float4*)(pr + 36);
  short8 a0, a1;
  a0[0] = f2bf(q0.x); a0[1] = f2bf(q0.y); a0[2] = f2bf(q0.z); a0[3] = f2bf(q0.w);
  a0[4] = f2bf(q1.x); a0[5] = f2bf(q1.y); a0[6] = f2bf(q1.z); a0[7] = f2bf(q1.w);
  a1[0] = f2bf(q2.x); a1[1] = f2bf(q2.y); a1[2] = f2bf(q2.z); a1[3] = f2bf(q2.w);
  a1[4] = f2bf(q3.x); a1[5] = f2bf(q3.y); a1[6] = f2bf(q3.z); a1[7] = f2bf(q3.w);

  float consv[4];
#pragma unroll
  for (int r = 0; r < 4; ++r) consv[r] = out[C_OFF + t0 + 4 * lg + r];

  float ssacc[4] = {0.f, 0.f, 0.f, 0.f};
  for (int dt2 = 0; dt2 < 32; ++dt2) {
    int dt = 32 * dq + dt2;
    const short8 b0 = *(const short8*)&eF[((dt * 2 + 0) * 64 + lane) * 8];
    const short8 b1v = *(const short8*)&eF[((dt * 2 + 1) * 64 + lane) * 8];
    f32x4 acc = {0.f, 0.f, 0.f, 0.f};
    acc = __builtin_amdgcn_mfma_f32_16x16x32_bf16(a0, b0, acc, 0, 0, 0);
    acc = __builtin_amdgcn_mfma_f32_16x16x32_bf16(a1, b1v, acc, 0, 0, 0);
    int d = 16 * dt + lr;
    float ebd = eb[d];
#pragma unroll
    for (int r = 0; r < 4; ++r) {
      int t = t0 + 4 * lg + r;
      float xv = x[(size_t)t * D + d];
      float yv = fmaf(acc[r] + ebd, consv[r], xv);
      out[Y_OFF + (size_t)t * D + d] = yv;
      ssacc[r] = fmaf(yv, yv, ssacc[r]);
    }
  }
#pragma unroll
  for (int r = 0; r < 4; ++r) {
    float s = ssacc[r];
    s += __shfl_xor(s, 1); s += __shfl_xor(s, 2);
    s += __shfl_xor(s, 4); s += __shfl_xor(s, 8);
    if (lr == 0) ssPart[dq * 16384 + t0 + 4 * lg + r] = s;
  }
}

// ---------------- K4: loss reduce ----------------
__global__ __launch_bounds__(256) void k4_loss(const float* __restrict__ lpart, float* __restrict__ loss) {
  __shared__ float w[4];
  float v = lpart[threadIdx.x];
  for (int o = 32; o > 0; o >>= 1) v += __shfl_down(v, o);
  if ((threadIdx.x & 63) == 0) w[threadIdx.x >> 6] = v;
  __syncthreads();
  if (threadIdx.x == 0)
    loss[0] = (w[0] + w[1] + w[2] + w[3]) * (1.0f / (16384.0f * 32.0f));
}

// ---------------- K5: RMSNorm rescale in place ----------------
__global__ __launch_bounds__(256) void k5_norm(float* __restrict__ y, const float* __restrict__ ssPart,
                                               const float* __restrict__ nw) {
  int t = blockIdx.x, tid = threadIdx.x;
  float ss = 0.f;
#pragma unroll
  for (int g = 0; g < 4; ++g) ss += ssPart[g * 16384 + t];
  float sc = rsqrtf(ss * (1.0f / 2048.0f) + 1e-6f);
#pragma unroll
  for (int r = 0; r < 2; ++r) {
    int d = (tid + 256 * r) * 4;
    float4 v = *(float4*)&y[(size_t)t * D + d];
    const float4 w = *(const float4*)&nw[d];
    v.x *= sc * w.x; v.y *= sc * w.y; v.z *= sc * w.z; v.w *= sc * w.w;
    *(float4*)&y[(size_t)t * D + d] = v;
  }
}

extern "C" void kernel_launch(void* const* d_in, const int* in_sizes, int n_in,
                              void* d_out, int out_size, void* d_ws, size_t ws_size,
                              hipStream_t stream) {
  (void)in_sizes; (void)n_in; (void)out_size; (void)ws_size;
  const float* x   = (const float*)d_in[0];
  const float* pw  = (const float*)d_in[1];
  const float* pb  = (const float*)d_in[2];
  const float* cm  = (const float*)d_in[3];
  const float* pol = (const float*)d_in[4];
  const float* w1  = (const float*)d_in[5];
  const float* b1  = (const float*)d_in[6];
  const float* w2  = (const float*)d_in[7];
  const float* b2  = (const float*)d_in[8];
  const float* cw  = (const float*)d_in[9];
  const float* cb  = (const float*)d_in[10];
  const float* ew  = (const float*)d_in[11];
  const float* eb  = (const float*)d_in[12];
  const float* nw  = (const float*)d_in[13];
  float* out = (float*)d_out;
  float* ws  = (float*)d_ws;

  hipLaunchKernelGGL(k0_prep, dim3(64), dim3(256), 0, stream, cm, pol, w1, w2, pw, ew, ws);
  // k1 writes sigmoided props0 into the y region of d_out (dead until k3 overwrites it)
  hipLaunchKernelGGL(k1_props, dim3(1024), dim3(256), 0, stream, x, ws, pb, out + Y_OFF);
  hipLaunchKernelGGL(k2_iter, dim3(256), dim3(512), 0, stream, ws, b1, b2, cw, cb,
                     out + Y_OFF, out, ws + WS_LPART);
  hipLaunchKernelGGL(k4_loss, dim3(1), dim3(256), 0, stream, ws + WS_LPART, out + L_OFF);
  hipLaunchKernelGGL(k3_emb, dim3(1024), dim3(256), 0, stream, x, ws, eb, out, ws + WS_SSP);
  hipLaunchKernelGGL(k5_norm, dim3(16384), dim3(256), 0, stream, out, ws + WS_SSP, nw);
}

// Round 4
// 159.104 us; speedup vs baseline: 5.7258x; 1.8440x over previous
//
#include <hip/hip_runtime.h>
#include <hip/hip_bf16.h>
#include <cstdint>

#define D     2048
#define NP    64
#define NC    32
#define T     16384

// d_out float offsets (y, props, satisfaction, consistency, loss)
#define Y_OFF   0
#define P_OFF   33554432
#define S_OFF   34603008
#define C_OFF   35127296
#define L_OFF   35143680

// ws float offsets
#define WS_LPART 0        // [1024]
#define WS_SUMP  1024     // [32] fp32
#define WS_PWF   1056     // bf16 frags [64 kc][4 jt][64 lane][8]
#define WS_EF    66592    // bf16 frags [128 dt][2 kc][64 lane][8]
#define WS_W1F   132128   // bf16 frags [8 nt][4 kc][64][8]
#define WS_W2F   140320   // bf16 frags [4 nt][4 kc][64][8]
#define WS_WMF   144416   // bf16 frags [2 nt][2 kc][64][8]
#define WS_WLF   145440   // bf16 frags [4 nt][64][8]
// end 146464 floats (~586 KB)

typedef short short8 __attribute__((ext_vector_type(8)));
typedef float f32x4 __attribute__((ext_vector_type(4)));

__device__ __forceinline__ float sigf(float z) { return 1.0f / (1.0f + __expf(-z)); }
__device__ __forceinline__ short f2bf(float f) {
  unsigned u = __float_as_uint(f);
  return (short)((u + 0x8000u) >> 16);
}
__device__ __forceinline__ unsigned pk2(float a, float b) {
  return ((unsigned)(unsigned short)f2bf(a)) | (((unsigned)(unsigned short)f2bf(b)) << 16);
}

// ---------------- K0: weight pre-transforms + MFMA B-fragment packing ----------------
__global__ __launch_bounds__(256) void k0_prep(const float* __restrict__ cm, const float* __restrict__ pol,
                                               const float* __restrict__ w1, const float* __restrict__ w2,
                                               const float* __restrict__ pw, const float* __restrict__ ew,
                                               float* __restrict__ ws) {
  int gid = blockIdx.x * 256 + threadIdx.x;
  int stride = gridDim.x * 256;
  // pwF: GEMM1 B-frag. (kc,jt,lane,e) -> pw[j=16jt+(l&15)][k=32kc+8*(l>>4)+e]
  short* pwF = (short*)(ws + WS_PWF);
  for (int idx = gid; idx < 64 * 4 * 64; idx += stride) {
    int kc = idx >> 8, jt = (idx >> 6) & 3, l = idx & 63;
    int j = 16 * jt + (l & 15), k = 32 * kc + 8 * (l >> 4);
    const float* src = &pw[(size_t)j * D + k];
    short8 v;
#pragma unroll
    for (int e = 0; e < 8; ++e) v[e] = f2bf(src[e]);
    *(short8*)&pwF[idx * 8] = v;
  }
  // eF: GEMM2 B-frag. (dt,kc,lane,e) -> emb_w[d=16dt+(l&15)][j=32kc+8*(l>>4)+e]
  short* eF = (short*)(ws + WS_EF);
  for (int idx = gid; idx < 128 * 2 * 64; idx += stride) {
    int dt = idx >> 7, kc = (idx >> 6) & 1, l = idx & 63;
    int d = 16 * dt + (l & 15), j = 32 * kc + 8 * (l >> 4);
    const float* src = &ew[(size_t)d * NP + j];
    short8 v;
#pragma unroll
    for (int e = 0; e < 8; ++e) v[e] = f2bf(src[e]);
    *(short8*)&eF[idx * 8] = v;
  }
  // w1F: (nt,kc,l,e) -> w1[m=16nt+(l&15)][k=32kc+8*(l>>4)+e]
  short* w1F = (short*)(ws + WS_W1F);
  for (int idx = gid; idx < 8 * 4 * 64; idx += stride) {
    int nt = idx >> 8, kc = (idx >> 6) & 3, l = idx & 63;
    int m = 16 * nt + (l & 15), k = 32 * kc + 8 * (l >> 4);
    const float* src = &w1[(size_t)m * 128 + k];
    short8 v;
#pragma unroll
    for (int e = 0; e < 8; ++e) v[e] = f2bf(src[e]);
    *(short8*)&w1F[idx * 8] = v;
  }
  // w2F: (nt,kc,l,e) -> w2[j=16nt+(l&15)][k=32kc+8*(l>>4)+e]
  short* w2F = (short*)(ws + WS_W2F);
  for (int idx = gid; idx < 4 * 4 * 64; idx += stride) {
    int nt = idx >> 8, kc = (idx >> 6) & 3, l = idx & 63;
    int j = 16 * nt + (l & 15), k = 32 * kc + 8 * (l >> 4);
    const float* src = &w2[(size_t)j * 128 + k];
    short8 v;
#pragma unroll
    for (int e = 0; e < 8; ++e) v[e] = f2bf(src[e]);
    *(short8*)&w2F[idx * 8] = v;
  }
  // wmF: sat B-frag. (nt,kc,l,e) -> (sig(cm)-sig(pol))[i=16nt+(l&15)][j=32kc+8*(l>>4)+e]
  short* wmF = (short*)(ws + WS_WMF);
  for (int idx = gid; idx < 2 * 2 * 64; idx += stride) {
    int nt = idx >> 7, kc = (idx >> 6) & 1, l = idx & 63;
    int i = 16 * nt + (l & 15), j = 32 * kc + 8 * (l >> 4);
    short8 v;
#pragma unroll
    for (int e = 0; e < 8; ++e)
      v[e] = f2bf(sigf(cm[i * 64 + j + e]) - sigf(pol[i * 64 + j + e]));
    *(short8*)&wmF[idx * 8] = v;
  }
  // wlF: viol B-frag. (nt,l,e) -> sig(cm)[i=8*(l>>4)+e][j=16nt+(l&15)]
  short* wlF = (short*)(ws + WS_WLF);
  for (int idx = gid; idx < 4 * 64; idx += stride) {
    int nt = idx >> 6, l = idx & 63;
    int j = 16 * nt + (l & 15), i0 = 8 * (l >> 4);
    short8 v;
#pragma unroll
    for (int e = 0; e < 8; ++e) v[e] = f2bf(sigf(cm[(i0 + e) * 64 + j]));
    *(short8*)&wlF[idx * 8] = v;
  }
  if (gid < NC) {
    float s = 0.f;
    for (int j = 0; j < NP; ++j) s += sigf(pol[gid * NP + j]);
    ws[WS_SUMP + gid] = s;
  }
}

// ---------------- K1: props0 = sigmoid(x @ prop_w.T + pb) via MFMA ----------------
__global__ __launch_bounds__(256) void k1_props(const float* __restrict__ x, const float* __restrict__ ws,
                                                const float* __restrict__ pb, float* __restrict__ props0) {
  int tid = threadIdx.x, lane = tid & 63;
  int jt = __builtin_amdgcn_readfirstlane(tid >> 6);
  int t0 = blockIdx.x * 16;
  int lr = lane & 15, lg = lane >> 4;
  const short* pwF = (const short*)(ws + WS_PWF);
  const float* xrow = x + (size_t)(t0 + lr) * D + 8 * lg;

  f32x4 acc = {0.f, 0.f, 0.f, 0.f};
  for (int kc = 0; kc < 64; ++kc) {
    const float* xp = xrow + 32 * kc;
    const float4 xa = *(const float4*)xp;
    const float4 xb = *(const float4*)(xp + 4);
    short8 a;
    a[0] = f2bf(xa.x); a[1] = f2bf(xa.y); a[2] = f2bf(xa.z); a[3] = f2bf(xa.w);
    a[4] = f2bf(xb.x); a[5] = f2bf(xb.y); a[6] = f2bf(xb.z); a[7] = f2bf(xb.w);
    const short8 b = *(const short8*)&pwF[((kc * 4 + jt) * 64 + lane) * 8];
    acc = __builtin_amdgcn_mfma_f32_16x16x32_bf16(a, b, acc, 0, 0, 0);
  }
  int j = 16 * jt + lr;
  float bj = pb[j];
#pragma unroll
  for (int r = 0; r < 4; ++r) {
    int t = t0 + 4 * lg + r;
    props0[(size_t)t * 64 + j] = sigf(acc[r] + bj);
  }
}

// ---------------- K2: correction iterations via MFMA; 1 wave = 16 tokens, wave-private ----------------
// LDS (per 64-thread block): H [16 t][128 k] bf16 @0 (256 B rows), H2 same @4096, SB [16][32] bf16 @8192.
// All bf16 tiles XOR-swizzled: byte_off ^= (row&7)<<4  (same formula on write and read).
__global__ __launch_bounds__(64) void k2_iter(const float* __restrict__ ws,
                                              const float* __restrict__ b1, const float* __restrict__ b2,
                                              const float* __restrict__ cw, const float* __restrict__ cb,
                                              const float* __restrict__ props0, float* __restrict__ out,
                                              float* __restrict__ lpart) {
  __shared__ char Lraw[9216];
  char* Hb = Lraw;
  char* H2b = Lraw + 4096;
  char* SBb = Lraw + 8192;
  int lane = threadIdx.x & 63;
  int lr = lane & 15, lg = lane >> 4;
  int t0 = blockIdx.x * 16;
  const short8* w1F = (const short8*)(ws + WS_W1F);
  const short8* w2F = (const short8*)(ws + WS_W2F);
  const short8* wmF = (const short8*)(ws + WS_WMF);
  const short8* wlF = (const short8*)(ws + WS_WLF);
  const float* SUMP = ws + WS_SUMP;

  // per-lane constant preloads
  float b1v[8], b2v[4], sumpv[2], cwv[2];
#pragma unroll
  for (int nt = 0; nt < 8; ++nt) b1v[nt] = b1[16 * nt + lr];
#pragma unroll
  for (int nt = 0; nt < 4; ++nt) b2v[nt] = b2[16 * nt + lr];
#pragma unroll
  for (int nt = 0; nt < 2; ++nt) { sumpv[nt] = SUMP[16 * nt + lr]; cwv[nt] = cw[16 * nt + lr]; }
  float cb0 = cb[0];

  // init: H[t][j] = bf16(props0), coalesced float4 loads
#pragma unroll
  for (int r = 0; r < 4; ++r) {
    int idx = r * 64 + lane;
    int t = idx >> 4, c4 = idx & 15;
    const float4 v = *(const float4*)&props0[(size_t)(t0 + t) * 64 + 4 * c4];
    int off = (t * 256 + c4 * 8) ^ ((t & 7) << 4);
    *(unsigned*)(Hb + off) = pk2(v.x, v.y);
    *(unsigned*)(Hb + off + 4) = pk2(v.z, v.w);
  }
  __syncthreads();

  const f32x4 zf = {0.f, 0.f, 0.f, 0.f};
  f32x4 s0, s1;

#define LDF(base, row, kelem, rowB) \
  (*(const short8*)((base) + ((((row) * (rowB)) + (kelem) * 2) ^ (((row) & 7) << 4))))
#define STBF(base, row, kelem, rowB, val) \
  (*(short*)((base) + ((((row) * (rowB)) + (kelem) * 2) ^ (((row) & 7) << 4))) = f2bf(val))

  for (int it = 0; it < 3; ++it) {
    // ---- sat -> SB (s_bar = 1 - sat)
    short8 ap0 = LDF(Hb, lr, 8 * lg, 256);
    short8 ap1 = LDF(Hb, lr, 32 + 8 * lg, 256);
    s0 = zf; s1 = zf;
    s0 = __builtin_amdgcn_mfma_f32_16x16x32_bf16(ap0, wmF[0 * 64 + lane], s0, 0, 0, 0);
    s0 = __builtin_amdgcn_mfma_f32_16x16x32_bf16(ap1, wmF[1 * 64 + lane], s0, 0, 0, 0);
    s1 = __builtin_amdgcn_mfma_f32_16x16x32_bf16(ap0, wmF[2 * 64 + lane], s1, 0, 0, 0);
    s1 = __builtin_amdgcn_mfma_f32_16x16x32_bf16(ap1, wmF[3 * 64 + lane], s1, 0, 0, 0);
#pragma unroll
    for (int q = 0; q < 4; ++q) {
      int t = 4 * lg + q;
      STBF(SBb, t, lr, 64, 1.f - (s0[q] + sumpv[0]) * (1.f / 64.f));
      STBF(SBb, t, 16 + lr, 64, 1.f - (s1[q] + sumpv[1]) * (1.f / 64.f));
    }
    __syncthreads();

    // ---- viol -> H[64..128)
    short8 as = LDF(SBb, lr, 8 * lg, 64);
    f32x4 vv0 = __builtin_amdgcn_mfma_f32_16x16x32_bf16(as, wlF[0 * 64 + lane], zf, 0, 0, 0);
    f32x4 vv1 = __builtin_amdgcn_mfma_f32_16x16x32_bf16(as, wlF[1 * 64 + lane], zf, 0, 0, 0);
    f32x4 vv2 = __builtin_amdgcn_mfma_f32_16x16x32_bf16(as, wlF[2 * 64 + lane], zf, 0, 0, 0);
    f32x4 vv3 = __builtin_amdgcn_mfma_f32_16x16x32_bf16(as, wlF[3 * 64 + lane], zf, 0, 0, 0);
    const float vs = 1.0f / (32.0f + 1e-6f);
#pragma unroll
    for (int q = 0; q < 4; ++q) {
      int t = 4 * lg + q;
      STBF(Hb, t, 64 + lr, 256, vv0[q] * vs);
      STBF(Hb, t, 64 + 16 + lr, 256, vv1[q] * vs);
      STBF(Hb, t, 64 + 32 + lr, 256, vv2[q] * vs);
      STBF(Hb, t, 64 + 48 + lr, 256, vv3[q] * vs);
    }
    __syncthreads();

    // ---- gemm1: h(128) @ w1T -> gelu -> H2
    short8 ah2 = LDF(Hb, lr, 64 + 8 * lg, 256);
    short8 ah3 = LDF(Hb, lr, 96 + 8 * lg, 256);
    f32x4 g1[8];
#pragma unroll
    for (int nt = 0; nt < 8; ++nt) {
      f32x4 a = zf;
      a = __builtin_amdgcn_mfma_f32_16x16x32_bf16(ap0, w1F[(nt * 4 + 0) * 64 + lane], a, 0, 0, 0);
      a = __builtin_amdgcn_mfma_f32_16x16x32_bf16(ap1, w1F[(nt * 4 + 1) * 64 + lane], a, 0, 0, 0);
      a = __builtin_amdgcn_mfma_f32_16x16x32_bf16(ah2, w1F[(nt * 4 + 2) * 64 + lane], a, 0, 0, 0);
      a = __builtin_amdgcn_mfma_f32_16x16x32_bf16(ah3, w1F[(nt * 4 + 3) * 64 + lane], a, 0, 0, 0);
      g1[nt] = a;
    }
#pragma unroll
    for (int nt = 0; nt < 8; ++nt) {
#pragma unroll
      for (int q = 0; q < 4; ++q) {
        float v = g1[nt][q] + b1v[nt];
        float gl = 0.5f * v * (1.0f + erff(v * 0.70710678118654752f));
        STBF(H2b, 4 * lg + q, 16 * nt + lr, 256, gl);
      }
    }
    __syncthreads();

    // ---- gemm2: h2(128) @ w2T -> sigmoid -> props (H low half)
    short8 ab0 = LDF(H2b, lr, 8 * lg, 256);
    short8 ab1 = LDF(H2b, lr, 32 + 8 * lg, 256);
    short8 ab2 = LDF(H2b, lr, 64 + 8 * lg, 256);
    short8 ab3 = LDF(H2b, lr, 96 + 8 * lg, 256);
#pragma unroll
    for (int nt = 0; nt < 4; ++nt) {
      f32x4 a = zf;
      a = __builtin_amdgcn_mfma_f32_16x16x32_bf16(ab0, w2F[(nt * 4 + 0) * 64 + lane], a, 0, 0, 0);
      a = __builtin_amdgcn_mfma_f32_16x16x32_bf16(ab1, w2F[(nt * 4 + 1) * 64 + lane], a, 0, 0, 0);
      a = __builtin_amdgcn_mfma_f32_16x16x32_bf16(ab2, w2F[(nt * 4 + 2) * 64 + lane], a, 0, 0, 0);
      a = __builtin_amdgcn_mfma_f32_16x16x32_bf16(ab3, w2F[(nt * 4 + 3) * 64 + lane], a, 0, 0, 0);
#pragma unroll
      for (int q = 0; q < 4; ++q) {
        int t = 4 * lg + q;
        float p = sigf(a[q] + b2v[nt]);
        STBF(Hb, t, 16 * nt + lr, 256, p);
        if (it == 2) out[P_OFF + (size_t)(t0 + t) * 64 + 16 * nt + lr] = p;
      }
    }
    __syncthreads();
  }

  // ---- final satisfaction + consistency + loss
  {
    short8 ap0 = LDF(Hb, lr, 8 * lg, 256);
    short8 ap1 = LDF(Hb, lr, 32 + 8 * lg, 256);
    s0 = zf; s1 = zf;
    s0 = __builtin_amdgcn_mfma_f32_16x16x32_bf16(ap0, wmF[0 * 64 + lane], s0, 0, 0, 0);
    s0 = __builtin_amdgcn_mfma_f32_16x16x32_bf16(ap1, wmF[1 * 64 + lane], s0, 0, 0, 0);
    s1 = __builtin_amdgcn_mfma_f32_16x16x32_bf16(ap0, wmF[2 * 64 + lane], s1, 0, 0, 0);
    s1 = __builtin_amdgcn_mfma_f32_16x16x32_bf16(ap1, wmF[3 * 64 + lane], s1, 0, 0, 0);
    float ls = 0.f;
    float csum[4];
#pragma unroll
    for (int q = 0; q < 4; ++q) {
      int t = 4 * lg + q;
      float sa = (s0[q] + sumpv[0]) * (1.f / 64.f);
      float sb = (s1[q] + sumpv[1]) * (1.f / 64.f);
      out[S_OFF + (size_t)(t0 + t) * 32 + lr] = sa;
      out[S_OFF + (size_t)(t0 + t) * 32 + 16 + lr] = sb;
      ls += (1.f - sa) + (1.f - sb);
      csum[q] = cwv[0] * sa + cwv[1] * sb;
    }
#pragma unroll
    for (int m = 1; m <= 8; m <<= 1) {
#pragma unroll
      for (int q = 0; q < 4; ++q) csum[q] += __shfl_xor(csum[q], m);
    }
    if (lr == 0) {
#pragma unroll
      for (int q = 0; q < 4; ++q)
        out[C_OFF + t0 + 4 * lg + q] = sigf(csum[q] + cb0);
    }
#pragma unroll
    for (int m = 1; m <= 32; m <<= 1) ls += __shfl_xor(ls, m);
    if (lane == 0) lpart[blockIdx.x] = ls;
  }
#undef LDF
#undef STBF
}

// ---------------- K3n: y = rmsnorm(x + (props@emb_w.T + eb)*cons) * nw, fused ----------------
// grid 1024 (16 tokens/block), 512 threads = 8 waves x 256 d. y held in regs; block-reduce ss.
__global__ __launch_bounds__(512) void k3n(const float* __restrict__ x, const float* __restrict__ ws,
                                           const float* __restrict__ eb, const float* __restrict__ nw,
                                           float* __restrict__ out) {
  __shared__ float ssp[8][16];
  __shared__ float sc16[16];
  int tid = threadIdx.x, lane = tid & 63;
  int wu = __builtin_amdgcn_readfirstlane(tid >> 6);
  int t0 = blockIdx.x * 16;
  int lr = lane & 15, lg = lane >> 4;
  const short* eF = (const short*)(ws + WS_EF);

  // A-frags from final props (fp32 [t][64])
  const float* pr = out + P_OFF + (size_t)(t0 + lr) * 64 + 8 * lg;
  const float4 q0 = *(const float4*)pr;
  const float4 q1 = *(const float4*)(pr + 4);
  const float4 q2 = *(const float4*)(pr + 32);
  const float4 q3 = *(const float4*)(pr + 36);
  short8 a0, a1;
  a0[0] = f2bf(q0.x); a0[1] = f2bf(q0.y); a0[2] = f2bf(q0.z); a0[3] = f2bf(q0.w);
  a0[4] = f2bf(q1.x); a0[5] = f2bf(q1.y); a0[6] = f2bf(q1.z); a0[7] = f2bf(q1.w);
  a1[0] = f2bf(q2.x); a1[1] = f2bf(q2.y); a1[2] = f2bf(q2.z); a1[3] = f2bf(q2.w);
  a1[4] = f2bf(q3.x); a1[5] = f2bf(q3.y); a1[6] = f2bf(q3.z); a1[7] = f2bf(q3.w);

  float consv[4];
#pragma unroll
  for (int r = 0; r < 4; ++r) consv[r] = out[C_OFF + t0 + 4 * lg + r];

  f32x4 yv[16];
  float ss[4] = {0.f, 0.f, 0.f, 0.f};
#pragma unroll
  for (int dt2 = 0; dt2 < 16; ++dt2) {
    int dt = wu * 16 + dt2;
    const short8 b0 = *(const short8*)&eF[((dt * 2 + 0) * 64 + lane) * 8];
    const short8 b1f = *(const short8*)&eF[((dt * 2 + 1) * 64 + lane) * 8];
    f32x4 acc = {0.f, 0.f, 0.f, 0.f};
    acc = __builtin_amdgcn_mfma_f32_16x16x32_bf16(a0, b0, acc, 0, 0, 0);
    acc = __builtin_amdgcn_mfma_f32_16x16x32_bf16(a1, b1f, acc, 0, 0, 0);
    int d = 16 * dt + lr;
    float ebd = eb[d];
    f32x4 y;
#pragma unroll
    for (int q = 0; q < 4; ++q) {
      float xvv = x[(size_t)(t0 + 4 * lg + q) * D + d];
      float val = fmaf(acc[q] + ebd, consv[q], xvv);
      y[q] = val;
      ss[q] = fmaf(val, val, ss[q]);
    }
    yv[dt2] = y;
  }
#pragma unroll
  for (int q = 0; q < 4; ++q) {
    float s = ss[q];
    s += __shfl_xor(s, 1); s += __shfl_xor(s, 2);
    s += __shfl_xor(s, 4); s += __shfl_xor(s, 8);
    if (lr == 0) ssp[wu][4 * lg + q] = s;
  }
  __syncthreads();
  if (tid < 16) {
    float s = 0.f;
#pragma unroll
    for (int w = 0; w < 8; ++w) s += ssp[w][tid];
    sc16[tid] = rsqrtf(s * (1.0f / 2048.0f) + 1e-6f);
  }
  __syncthreads();
  float scq[4];
#pragma unroll
  for (int q = 0; q < 4; ++q) scq[q] = sc16[4 * lg + q];
#pragma unroll
  for (int dt2 = 0; dt2 < 16; ++dt2) {
    int dt = wu * 16 + dt2;
    int d = 16 * dt + lr;
    float nwv = nw[d];
#pragma unroll
    for (int q = 0; q < 4; ++q)
      out[Y_OFF + (size_t)(t0 + 4 * lg + q) * D + d] = yv[dt2][q] * scq[q] * nwv;
  }
}

// ---------------- K4: loss reduce (1024 partials) ----------------
__global__ __launch_bounds__(256) void k4_loss(const float* __restrict__ lpart, float* __restrict__ loss) {
  __shared__ float w[4];
  int tid = threadIdx.x;
  float v = 0.f;
#pragma unroll
  for (int r = 0; r < 4; ++r) v += lpart[tid + 256 * r];
  for (int o = 32; o > 0; o >>= 1) v += __shfl_down(v, o);
  if ((tid & 63) == 0) w[tid >> 6] = v;
  __syncthreads();
  if (tid == 0)
    loss[0] = (w[0] + w[1] + w[2] + w[3]) * (1.0f / (16384.0f * 32.0f));
}

extern "C" void kernel_launch(void* const* d_in, const int* in_sizes, int n_in,
                              void* d_out, int out_size, void* d_ws, size_t ws_size,
                              hipStream_t stream) {
  (void)in_sizes; (void)n_in; (void)out_size; (void)ws_size;
  const float* x   = (const float*)d_in[0];
  const float* pw  = (const float*)d_in[1];
  const float* pb  = (const float*)d_in[2];
  const float* cm  = (const float*)d_in[3];
  const float* pol = (const float*)d_in[4];
  const float* w1  = (const float*)d_in[5];
  const float* b1  = (const float*)d_in[6];
  const float* w2  = (const float*)d_in[7];
  const float* b2  = (const float*)d_in[8];
  const float* cw  = (const float*)d_in[9];
  const float* cb  = (const float*)d_in[10];
  const float* ew  = (const float*)d_in[11];
  const float* eb  = (const float*)d_in[12];
  const float* nw  = (const float*)d_in[13];
  float* out = (float*)d_out;
  float* ws  = (float*)d_ws;

  hipLaunchKernelGGL(k0_prep, dim3(64), dim3(256), 0, stream, cm, pol, w1, w2, pw, ew, ws);
  // k1 writes sigmoided props0 into the y region of d_out (dead until k3n overwrites it)
  hipLaunchKernelGGL(k1_props, dim3(1024), dim3(256), 0, stream, x, ws, pb, out + Y_OFF);
  hipLaunchKernelGGL(k2_iter, dim3(1024), dim3(64), 0, stream, ws, b1, b2, cw, cb,
                     out + Y_OFF, out, ws + WS_LPART);
  hipLaunchKernelGGL(k4_loss, dim3(1), dim3(256), 0, stream, ws + WS_LPART, out + L_OFF);
  hipLaunchKernelGGL(k3n, dim3(1024), dim3(512), 0, stream, x, ws, eb, nw, out);
}

// Round 5
// 128.934 us; speedup vs baseline: 7.0656x; 1.2340x over previous
//
#include <hip/hip_runtime.h>
#include <hip/hip_bf16.h>
#include <cstdint>

#define D     2048
#define NP    64
#define NC    32
#define T     16384

// d_out float offsets (y, props, satisfaction, consistency, loss)
#define Y_OFF   0
#define P_OFF   33554432
#define S_OFF   34603008
#define C_OFF   35127296
#define L_OFF   35143680

// ws float offsets
#define WS_LPART 0        // [1024]
#define WS_SUMP  1024     // [32] fp32
#define WS_PWF   1056     // bf16 frags [64 kc][4 jt][64 lane][8]
#define WS_EF    66592    // bf16 frags [128 dt][2 kc][64 lane][8]
#define WS_W1F   132128   // bf16 frags [8 nt][4 kc][64][8]
#define WS_W2F   140320   // bf16 frags [4 nt][4 kc][64][8]
#define WS_WMF   144416   // bf16 frags [2 nt][2 kc][64][8]
#define WS_WLF   145440   // bf16 frags [4 nt][64][8]
// end 146464 floats (~586 KB)

typedef short short8 __attribute__((ext_vector_type(8)));
typedef float f32x4 __attribute__((ext_vector_type(4)));

__device__ __forceinline__ float sigf(float z) { return 1.0f / (1.0f + __expf(-z)); }
__device__ __forceinline__ short f2bf(float f) {
  unsigned u = __float_as_uint(f);
  return (short)((u + 0x8000u) >> 16);
}
__device__ __forceinline__ unsigned pk2(float a, float b) {
  return ((unsigned)(unsigned short)f2bf(a)) | (((unsigned)(unsigned short)f2bf(b)) << 16);
}

// ---------------- K0: weight pre-transforms + MFMA B-fragment packing ----------------
__global__ __launch_bounds__(256) void k0_prep(const float* __restrict__ cm, const float* __restrict__ pol,
                                               const float* __restrict__ w1, const float* __restrict__ w2,
                                               const float* __restrict__ pw, const float* __restrict__ ew,
                                               float* __restrict__ ws) {
  int gid = blockIdx.x * 256 + threadIdx.x;
  int stride = gridDim.x * 256;
  // pwF: GEMM1 W-frag. (kc,jt,lane,e) -> pw[j=16jt+(l&15)][k=32kc+8*(l>>4)+e]
  short* pwF = (short*)(ws + WS_PWF);
  for (int idx = gid; idx < 64 * 4 * 64; idx += stride) {
    int kc = idx >> 8, jt = (idx >> 6) & 3, l = idx & 63;
    int j = 16 * jt + (l & 15), k = 32 * kc + 8 * (l >> 4);
    const float* src = &pw[(size_t)j * D + k];
    short8 v;
#pragma unroll
    for (int e = 0; e < 8; ++e) v[e] = f2bf(src[e]);
    *(short8*)&pwF[idx * 8] = v;
  }
  // eF: GEMM2 W-frag. (dt,kc,lane,e) -> emb_w[d=16dt+(l&15)][j=32kc+8*(l>>4)+e]
  short* eF = (short*)(ws + WS_EF);
  for (int idx = gid; idx < 128 * 2 * 64; idx += stride) {
    int dt = idx >> 7, kc = (idx >> 6) & 1, l = idx & 63;
    int d = 16 * dt + (l & 15), j = 32 * kc + 8 * (l >> 4);
    const float* src = &ew[(size_t)d * NP + j];
    short8 v;
#pragma unroll
    for (int e = 0; e < 8; ++e) v[e] = f2bf(src[e]);
    *(short8*)&eF[idx * 8] = v;
  }
  // w1F: (nt,kc,l,e) -> w1[m=16nt+(l&15)][k=32kc+8*(l>>4)+e]
  short* w1F = (short*)(ws + WS_W1F);
  for (int idx = gid; idx < 8 * 4 * 64; idx += stride) {
    int nt = idx >> 8, kc = (idx >> 6) & 3, l = idx & 63;
    int m = 16 * nt + (l & 15), k = 32 * kc + 8 * (l >> 4);
    const float* src = &w1[(size_t)m * 128 + k];
    short8 v;
#pragma unroll
    for (int e = 0; e < 8; ++e) v[e] = f2bf(src[e]);
    *(short8*)&w1F[idx * 8] = v;
  }
  // w2F: (nt,kc,l,e) -> w2[j=16nt+(l&15)][k=32kc+8*(l>>4)+e]
  short* w2F = (short*)(ws + WS_W2F);
  for (int idx = gid; idx < 4 * 4 * 64; idx += stride) {
    int nt = idx >> 8, kc = (idx >> 6) & 3, l = idx & 63;
    int j = 16 * nt + (l & 15), k = 32 * kc + 8 * (l >> 4);
    const float* src = &w2[(size_t)j * 128 + k];
    short8 v;
#pragma unroll
    for (int e = 0; e < 8; ++e) v[e] = f2bf(src[e]);
    *(short8*)&w2F[idx * 8] = v;
  }
  // wmF: sat W-frag. (nt,kc,l,e) -> (sig(cm)-sig(pol))[i=16nt+(l&15)][j=32kc+8*(l>>4)+e]
  short* wmF = (short*)(ws + WS_WMF);
  for (int idx = gid; idx < 2 * 2 * 64; idx += stride) {
    int nt = idx >> 7, kc = (idx >> 6) & 1, l = idx & 63;
    int i = 16 * nt + (l & 15), j = 32 * kc + 8 * (l >> 4);
    short8 v;
#pragma unroll
    for (int e = 0; e < 8; ++e)
      v[e] = f2bf(sigf(cm[i * 64 + j + e]) - sigf(pol[i * 64 + j + e]));
    *(short8*)&wmF[idx * 8] = v;
  }
  // wlF: viol W-frag. (nt,l,e) -> sig(cm)[i=8*(l>>4)+e][j=16nt+(l&15)]
  short* wlF = (short*)(ws + WS_WLF);
  for (int idx = gid; idx < 4 * 64; idx += stride) {
    int nt = idx >> 6, l = idx & 63;
    int j = 16 * nt + (l & 15), i0 = 8 * (l >> 4);
    short8 v;
#pragma unroll
    for (int e = 0; e < 8; ++e) v[e] = f2bf(sigf(cm[(i0 + e) * 64 + j]));
    *(short8*)&wlF[idx * 8] = v;
  }
  if (gid < NC) {
    float s = 0.f;
    for (int j = 0; j < NP; ++j) s += sigf(pol[gid * NP + j]);
    ws[WS_SUMP + gid] = s;
  }
}

// ---------------- K1: props0 = sigmoid(x @ prop_w.T + pb) via MFMA, LDS-staged x ----------------
// grid 1024 (16 tokens/block), 4 waves = 4 j-tiles. x chunk [16t][256k] bf16 in LDS, XOR-swizzled.
// Operands swapped: C = W * x^T -> lane holds (col=token lr, rows j = 16jt+4lg+q) -> float4 stores.
__global__ __launch_bounds__(256) void k1_props(const float* __restrict__ x, const float* __restrict__ ws,
                                                const float* __restrict__ pb, float* __restrict__ props0) {
  __shared__ char XT[8192];  // [16][256] bf16, byte_off ^= (row&7)<<4
  int tid = threadIdx.x, lane = tid & 63;
  int jt = __builtin_amdgcn_readfirstlane(tid >> 6);
  int wv = tid >> 6;
  int t0 = blockIdx.x * 16;
  int lr = lane & 15, lg = lane >> 4;
  int c64 = tid & 63;
  const short* pwF = (const short*)(ws + WS_PWF);

  f32x4 acc = {0.f, 0.f, 0.f, 0.f};
  for (int c = 0; c < 8; ++c) {
    // coalesced load of chunk rows: thread -> tokens wv,wv+4,wv+8,wv+12, cols 4*c64
    float4 st[4];
#pragma unroll
    for (int j = 0; j < 4; ++j)
      st[j] = *(const float4*)&x[(size_t)(t0 + wv + 4 * j) * D + 256 * c + 4 * c64];
    __syncthreads();  // prior chunk's ds_reads complete before overwrite
#pragma unroll
    for (int j = 0; j < 4; ++j) {
      int tt = wv + 4 * j;
      int off = (tt * 512 + 8 * c64) ^ ((tt & 7) << 4);
      uint2 p = make_uint2(pk2(st[j].x, st[j].y), pk2(st[j].z, st[j].w));
      *(uint2*)(XT + off) = p;
    }
    __syncthreads();
#pragma unroll
    for (int kcL = 0; kcL < 8; ++kcL) {
      const short8 b = *(const short8*)(XT + ((lr * 512 + 64 * kcL + 16 * lg) ^ ((lr & 7) << 4)));
      const short8 a = *(const short8*)&pwF[(((8 * c + kcL) * 4 + jt) * 64 + lane) * 8];
      acc = __builtin_amdgcn_mfma_f32_16x16x32_bf16(a, b, acc, 0, 0, 0);
    }
  }
  // epilogue: lane holds j = 16jt+4lg+q for token t0+lr
  int j0 = 16 * jt + 4 * lg;
  const float4 pbv = *(const float4*)&pb[j0];
  float4 o;
  o.x = sigf(acc[0] + pbv.x); o.y = sigf(acc[1] + pbv.y);
  o.z = sigf(acc[2] + pbv.z); o.w = sigf(acc[3] + pbv.w);
  *(float4*)&props0[(size_t)(t0 + lr) * 64 + j0] = o;
}

// ---------------- K2: correction iterations via MFMA; 1 wave = 16 tokens, wave-private ----------------
__global__ __launch_bounds__(64) void k2_iter(const float* __restrict__ ws,
                                              const float* __restrict__ b1, const float* __restrict__ b2,
                                              const float* __restrict__ cw, const float* __restrict__ cb,
                                              const float* __restrict__ props0, float* __restrict__ out,
                                              float* __restrict__ lpart) {
  __shared__ char Lraw[9216];
  char* Hb = Lraw;
  char* H2b = Lraw + 4096;
  char* SBb = Lraw + 8192;
  int lane = threadIdx.x & 63;
  int lr = lane & 15, lg = lane >> 4;
  int t0 = blockIdx.x * 16;
  const short8* w1F = (const short8*)(ws + WS_W1F);
  const short8* w2F = (const short8*)(ws + WS_W2F);
  const short8* wmF = (const short8*)(ws + WS_WMF);
  const short8* wlF = (const short8*)(ws + WS_WLF);
  const float* SUMP = ws + WS_SUMP;

  float b1v[8], b2v[4], sumpv[2], cwv[2];
#pragma unroll
  for (int nt = 0; nt < 8; ++nt) b1v[nt] = b1[16 * nt + lr];
#pragma unroll
  for (int nt = 0; nt < 4; ++nt) b2v[nt] = b2[16 * nt + lr];
#pragma unroll
  for (int nt = 0; nt < 2; ++nt) { sumpv[nt] = SUMP[16 * nt + lr]; cwv[nt] = cw[16 * nt + lr]; }
  float cb0 = cb[0];

#pragma unroll
  for (int r = 0; r < 4; ++r) {
    int idx = r * 64 + lane;
    int t = idx >> 4, c4 = idx & 15;
    const float4 v = *(const float4*)&props0[(size_t)(t0 + t) * 64 + 4 * c4];
    int off = (t * 256 + c4 * 8) ^ ((t & 7) << 4);
    *(unsigned*)(Hb + off) = pk2(v.x, v.y);
    *(unsigned*)(Hb + off + 4) = pk2(v.z, v.w);
  }
  __syncthreads();

  const f32x4 zf = {0.f, 0.f, 0.f, 0.f};
  f32x4 s0, s1;

#define LDF(base, row, kelem, rowB) \
  (*(const short8*)((base) + ((((row) * (rowB)) + (kelem) * 2) ^ (((row) & 7) << 4))))
#define STBF(base, row, kelem, rowB, val) \
  (*(short*)((base) + ((((row) * (rowB)) + (kelem) * 2) ^ (((row) & 7) << 4))) = f2bf(val))

  for (int it = 0; it < 3; ++it) {
    short8 ap0 = LDF(Hb, lr, 8 * lg, 256);
    short8 ap1 = LDF(Hb, lr, 32 + 8 * lg, 256);
    s0 = zf; s1 = zf;
    s0 = __builtin_amdgcn_mfma_f32_16x16x32_bf16(ap0, wmF[0 * 64 + lane], s0, 0, 0, 0);
    s0 = __builtin_amdgcn_mfma_f32_16x16x32_bf16(ap1, wmF[1 * 64 + lane], s0, 0, 0, 0);
    s1 = __builtin_amdgcn_mfma_f32_16x16x32_bf16(ap0, wmF[2 * 64 + lane], s1, 0, 0, 0);
    s1 = __builtin_amdgcn_mfma_f32_16x16x32_bf16(ap1, wmF[3 * 64 + lane], s1, 0, 0, 0);
#pragma unroll
    for (int q = 0; q < 4; ++q) {
      int t = 4 * lg + q;
      STBF(SBb, t, lr, 64, 1.f - (s0[q] + sumpv[0]) * (1.f / 64.f));
      STBF(SBb, t, 16 + lr, 64, 1.f - (s1[q] + sumpv[1]) * (1.f / 64.f));
    }
    __syncthreads();

    short8 as = LDF(SBb, lr, 8 * lg, 64);
    f32x4 vv0 = __builtin_amdgcn_mfma_f32_16x16x32_bf16(as, wlF[0 * 64 + lane], zf, 0, 0, 0);
    f32x4 vv1 = __builtin_amdgcn_mfma_f32_16x16x32_bf16(as, wlF[1 * 64 + lane], zf, 0, 0, 0);
    f32x4 vv2 = __builtin_amdgcn_mfma_f32_16x16x32_bf16(as, wlF[2 * 64 + lane], zf, 0, 0, 0);
    f32x4 vv3 = __builtin_amdgcn_mfma_f32_16x16x32_bf16(as, wlF[3 * 64 + lane], zf, 0, 0, 0);
    const float vs = 1.0f / (32.0f + 1e-6f);
#pragma unroll
    for (int q = 0; q < 4; ++q) {
      int t = 4 * lg + q;
      STBF(Hb, t, 64 + lr, 256, vv0[q] * vs);
      STBF(Hb, t, 64 + 16 + lr, 256, vv1[q] * vs);
      STBF(Hb, t, 64 + 32 + lr, 256, vv2[q] * vs);
      STBF(Hb, t, 64 + 48 + lr, 256, vv3[q] * vs);
    }
    __syncthreads();

    short8 ah2 = LDF(Hb, lr, 64 + 8 * lg, 256);
    short8 ah3 = LDF(Hb, lr, 96 + 8 * lg, 256);
    f32x4 g1[8];
#pragma unroll
    for (int nt = 0; nt < 8; ++nt) {
      f32x4 a = zf;
      a = __builtin_amdgcn_mfma_f32_16x16x32_bf16(ap0, w1F[(nt * 4 + 0) * 64 + lane], a, 0, 0, 0);
      a = __builtin_amdgcn_mfma_f32_16x16x32_bf16(ap1, w1F[(nt * 4 + 1) * 64 + lane], a, 0, 0, 0);
      a = __builtin_amdgcn_mfma_f32_16x16x32_bf16(ah2, w1F[(nt * 4 + 2) * 64 + lane], a, 0, 0, 0);
      a = __builtin_amdgcn_mfma_f32_16x16x32_bf16(ah3, w1F[(nt * 4 + 3) * 64 + lane], a, 0, 0, 0);
      g1[nt] = a;
    }
#pragma unroll
    for (int nt = 0; nt < 8; ++nt) {
#pragma unroll
      for (int q = 0; q < 4; ++q) {
        float v = g1[nt][q] + b1v[nt];
        float gl = 0.5f * v * (1.0f + erff(v * 0.70710678118654752f));
        STBF(H2b, 4 * lg + q, 16 * nt + lr, 256, gl);
      }
    }
    __syncthreads();

    short8 ab0 = LDF(H2b, lr, 8 * lg, 256);
    short8 ab1 = LDF(H2b, lr, 32 + 8 * lg, 256);
    short8 ab2 = LDF(H2b, lr, 64 + 8 * lg, 256);
    short8 ab3 = LDF(H2b, lr, 96 + 8 * lg, 256);
#pragma unroll
    for (int nt = 0; nt < 4; ++nt) {
      f32x4 a = zf;
      a = __builtin_amdgcn_mfma_f32_16x16x32_bf16(ab0, w2F[(nt * 4 + 0) * 64 + lane], a, 0, 0, 0);
      a = __builtin_amdgcn_mfma_f32_16x16x32_bf16(ab1, w2F[(nt * 4 + 1) * 64 + lane], a, 0, 0, 0);
      a = __builtin_amdgcn_mfma_f32_16x16x32_bf16(ab2, w2F[(nt * 4 + 2) * 64 + lane], a, 0, 0, 0);
      a = __builtin_amdgcn_mfma_f32_16x16x32_bf16(ab3, w2F[(nt * 4 + 3) * 64 + lane], a, 0, 0, 0);
#pragma unroll
      for (int q = 0; q < 4; ++q) {
        int t = 4 * lg + q;
        float p = sigf(a[q] + b2v[nt]);
        STBF(Hb, t, 16 * nt + lr, 256, p);
        if (it == 2) out[P_OFF + (size_t)(t0 + t) * 64 + 16 * nt + lr] = p;
      }
    }
    __syncthreads();
  }

  {
    short8 ap0 = LDF(Hb, lr, 8 * lg, 256);
    short8 ap1 = LDF(Hb, lr, 32 + 8 * lg, 256);
    s0 = zf; s1 = zf;
    s0 = __builtin_amdgcn_mfma_f32_16x16x32_bf16(ap0, wmF[0 * 64 + lane], s0, 0, 0, 0);
    s0 = __builtin_amdgcn_mfma_f32_16x16x32_bf16(ap1, wmF[1 * 64 + lane], s0, 0, 0, 0);
    s1 = __builtin_amdgcn_mfma_f32_16x16x32_bf16(ap0, wmF[2 * 64 + lane], s1, 0, 0, 0);
    s1 = __builtin_amdgcn_mfma_f32_16x16x32_bf16(ap1, wmF[3 * 64 + lane], s1, 0, 0, 0);
    float ls = 0.f;
    float csum[4];
#pragma unroll
    for (int q = 0; q < 4; ++q) {
      int t = 4 * lg + q;
      float sa = (s0[q] + sumpv[0]) * (1.f / 64.f);
      float sb = (s1[q] + sumpv[1]) * (1.f / 64.f);
      out[S_OFF + (size_t)(t0 + t) * 32 + lr] = sa;
      out[S_OFF + (size_t)(t0 + t) * 32 + 16 + lr] = sb;
      ls += (1.f - sa) + (1.f - sb);
      csum[q] = cwv[0] * sa + cwv[1] * sb;
    }
#pragma unroll
    for (int m = 1; m <= 8; m <<= 1) {
#pragma unroll
      for (int q = 0; q < 4; ++q) csum[q] += __shfl_xor(csum[q], m);
    }
    if (lr == 0) {
#pragma unroll
      for (int q = 0; q < 4; ++q)
        out[C_OFF + t0 + 4 * lg + q] = sigf(csum[q] + cb0);
    }
#pragma unroll
    for (int m = 1; m <= 32; m <<= 1) ls += __shfl_xor(ls, m);
    if (lane == 0) lpart[blockIdx.x] = ls;
  }
#undef LDF
#undef STBF
}

// ---------------- K3n: y = rmsnorm(x + (props@emb_w.T + eb)*cons) * nw, fused ----------------
// grid 1024 (16 tokens/block), 512 threads = 8 waves x 256 d. Swapped MFMA: C = emb * props^T
// -> lane holds (col=token lr, rows d = 16dt+4lg+q) -> float4 x/y access.
__global__ __launch_bounds__(512) void k3n(const float* __restrict__ x, const float* __restrict__ ws,
                                           const float* __restrict__ eb, const float* __restrict__ nw,
                                           float* __restrict__ out) {
  __shared__ float ssp[8][16];
  __shared__ float sc16[16];
  int tid = threadIdx.x, lane = tid & 63;
  int wu = __builtin_amdgcn_readfirstlane(tid >> 6);
  int t0 = blockIdx.x * 16;
  int lr = lane & 15, lg = lane >> 4;
  const short* eF = (const short*)(ws + WS_EF);

  // props fragments (B operand): B[l][e] = props[t0+(l&15)][32kc + 8*(l>>4)+e]
  const float* pr = out + P_OFF + (size_t)(t0 + lr) * 64 + 8 * lg;
  const float4 q0 = *(const float4*)pr;
  const float4 q1 = *(const float4*)(pr + 4);
  const float4 q2 = *(const float4*)(pr + 32);
  const float4 q3 = *(const float4*)(pr + 36);
  short8 p0, p1;
  p0[0] = f2bf(q0.x); p0[1] = f2bf(q0.y); p0[2] = f2bf(q0.z); p0[3] = f2bf(q0.w);
  p0[4] = f2bf(q1.x); p0[5] = f2bf(q1.y); p0[6] = f2bf(q1.z); p0[7] = f2bf(q1.w);
  p1[0] = f2bf(q2.x); p1[1] = f2bf(q2.y); p1[2] = f2bf(q2.z); p1[3] = f2bf(q2.w);
  p1[4] = f2bf(q3.x); p1[5] = f2bf(q3.y); p1[6] = f2bf(q3.z); p1[7] = f2bf(q3.w);

  float consv = out[C_OFF + t0 + lr];

  f32x4 yv[16];
  float ss = 0.f;
#pragma unroll
  for (int dt2 = 0; dt2 < 16; ++dt2) {
    int dt = wu * 16 + dt2;
    const short8 e0 = *(const short8*)&eF[((dt * 2 + 0) * 64 + lane) * 8];
    const short8 e1 = *(const short8*)&eF[((dt * 2 + 1) * 64 + lane) * 8];
    f32x4 acc = {0.f, 0.f, 0.f, 0.f};
    acc = __builtin_amdgcn_mfma_f32_16x16x32_bf16(e0, p0, acc, 0, 0, 0);
    acc = __builtin_amdgcn_mfma_f32_16x16x32_bf16(e1, p1, acc, 0, 0, 0);
    int d0 = 16 * dt + 4 * lg;
    const float4 ebv = *(const float4*)&eb[d0];
    const float4 xv = *(const float4*)&x[(size_t)(t0 + lr) * D + d0];
    f32x4 y;
    y[0] = fmaf(acc[0] + ebv.x, consv, xv.x);
    y[1] = fmaf(acc[1] + ebv.y, consv, xv.y);
    y[2] = fmaf(acc[2] + ebv.z, consv, xv.z);
    y[3] = fmaf(acc[3] + ebv.w, consv, xv.w);
    ss += y[0] * y[0] + y[1] * y[1] + y[2] * y[2] + y[3] * y[3];
    yv[dt2] = y;
  }
  // reduce ss over the 4 lg groups (lanes lr, lr+16, lr+32, lr+48)
  ss += __shfl_xor(ss, 16);
  ss += __shfl_xor(ss, 32);
  if (lg == 0) ssp[wu][lr] = ss;
  __syncthreads();
  if (tid < 16) {
    float s = 0.f;
#pragma unroll
    for (int w = 0; w < 8; ++w) s += ssp[w][tid];
    sc16[tid] = rsqrtf(s * (1.0f / 2048.0f) + 1e-6f);
  }
  __syncthreads();
  float sc = sc16[lr];
#pragma unroll
  for (int dt2 = 0; dt2 < 16; ++dt2) {
    int d0 = 16 * (wu * 16 + dt2) + 4 * lg;
    const float4 nwv = *(const float4*)&nw[d0];
    float4 o;
    o.x = yv[dt2][0] * sc * nwv.x;
    o.y = yv[dt2][1] * sc * nwv.y;
    o.z = yv[dt2][2] * sc * nwv.z;
    o.w = yv[dt2][3] * sc * nwv.w;
    *(float4*)&out[Y_OFF + (size_t)(t0 + lr) * D + d0] = o;
  }
}

// ---------------- K4: loss reduce (1024 partials) ----------------
__global__ __launch_bounds__(256) void k4_loss(const float* __restrict__ lpart, float* __restrict__ loss) {
  __shared__ float w[4];
  int tid = threadIdx.x;
  float v = 0.f;
#pragma unroll
  for (int r = 0; r < 4; ++r) v += lpart[tid + 256 * r];
  for (int o = 32; o > 0; o >>= 1) v += __shfl_down(v, o);
  if ((tid & 63) == 0) w[tid >> 6] = v;
  __syncthreads();
  if (tid == 0)
    loss[0] = (w[0] + w[1] + w[2] + w[3]) * (1.0f / (16384.0f * 32.0f));
}

extern "C" void kernel_launch(void* const* d_in, const int* in_sizes, int n_in,
                              void* d_out, int out_size, void* d_ws, size_t ws_size,
                              hipStream_t stream) {
  (void)in_sizes; (void)n_in; (void)out_size; (void)ws_size;
  const float* x   = (const float*)d_in[0];
  const float* pw  = (const float*)d_in[1];
  const float* pb  = (const float*)d_in[2];
  const float* cm  = (const float*)d_in[3];
  const float* pol = (const float*)d_in[4];
  const float* w1  = (const float*)d_in[5];
  const float* b1  = (const float*)d_in[6];
  const float* w2  = (const float*)d_in[7];
  const float* b2  = (const float*)d_in[8];
  const float* cw  = (const float*)d_in[9];
  const float* cb  = (const float*)d_in[10];
  const float* ew  = (const float*)d_in[11];
  const float* eb  = (const float*)d_in[12];
  const float* nw  = (const float*)d_in[13];
  float* out = (float*)d_out;
  float* ws  = (float*)d_ws;

  hipLaunchKernelGGL(k0_prep, dim3(64), dim3(256), 0, stream, cm, pol, w1, w2, pw, ew, ws);
  // k1 writes sigmoided props0 into the y region of d_out (dead until k3n overwrites it)
  hipLaunchKernelGGL(k1_props, dim3(1024), dim3(256), 0, stream, x, ws, pb, out + Y_OFF);
  hipLaunchKernelGGL(k2_iter, dim3(1024), dim3(64), 0, stream, ws, b1, b2, cw, cb,
                     out + Y_OFF, out, ws + WS_LPART);
  hipLaunchKernelGGL(k4_loss, dim3(1), dim3(256), 0, stream, ws + WS_LPART, out + L_OFF);
  hipLaunchKernelGGL(k3n, dim3(1024), dim3(512), 0, stream, x, ws, eb, nw, out);
}